// Round 9
// baseline (560.863 us; speedup 1.0000x reference)
//
#include <hip/hip_runtime.h>
#include <hip/hip_bf16.h>

typedef __bf16 bf16;
typedef __attribute__((ext_vector_type(4))) __bf16 bf16x4;
typedef __attribute__((ext_vector_type(8))) __bf16 bf16x8;
typedef __attribute__((ext_vector_type(4))) float f32x4;

__device__ inline void gload_lds16(const bf16* g, bf16* l) {
    __builtin_amdgcn_global_load_lds(
        (const __attribute__((address_space(1))) void*)g,
        (__attribute__((address_space(3))) void*)l, 16, 0, 0);
}

// ---------------------------------------------------------------- fused conversions
struct CvtArgs {
    const float* src[6];
    bf16* dst[6];
    long n4[6];
    float scale[6];
};
__global__ void cvt_all(CvtArgs a) {
    int j = blockIdx.y;
    const float* __restrict__ src = a.src[j];
    bf16* __restrict__ dst = a.dst[j];
    long n4 = a.n4[j];
    float sc = a.scale[j];
    long i = (long)blockIdx.x * blockDim.x + threadIdx.x;
    long stride = (long)gridDim.x * blockDim.x;
    for (; i < n4; i += stride) {
        float4 v = ((const float4*)src)[i];
        bf16x4 o = { (bf16)(v.x * sc), (bf16)(v.y * sc), (bf16)(v.z * sc), (bf16)(v.w * sc) };
        ((bf16x4*)dst)[i] = o;
    }
}

// ---------------------------------------------------------------- embedding
__global__ void embed_kernel(const int* __restrict__ x, const float* __restrict__ we,
                             const float* __restrict__ pe, float* __restrict__ emb_f,
                             bf16* __restrict__ emb_b) {
    int row = blockIdx.x;            // 0..8191  (b*2048 + s)
    int c   = threadIdx.x;           // 0..127
    int tok = x[row];
    int s   = row & 2047;
    float4 w = ((const float4*)we)[(long)tok * 128 + c];
    float4 p = ((const float4*)pe)[(long)s * 128 + c];
    float4 e = { w.x + p.x, w.y + p.y, w.z + p.z, w.w + p.w };
    ((float4*)emb_f)[(long)row * 128 + c] = e;
    bf16x4 eb = { (bf16)e.x, (bf16)e.y, (bf16)e.z, (bf16)e.w };
    ((bf16x4*)emb_b)[(long)row * 128 + c] = eb;
}

// ---------------------------------------------------------------- layernorm
template<bool WF32>
__global__ void ln_kernel(const float* __restrict__ a, const float* __restrict__ bres,
                          const float* __restrict__ g, const float* __restrict__ bb,
                          float* __restrict__ of, bf16* __restrict__ ob) {
    int row = blockIdx.x;            // 8192
    int t   = threadIdx.x;           // 128
    float4 xa = ((const float4*)a)[(long)row * 128 + t];
    float4 xb = ((const float4*)bres)[(long)row * 128 + t];
    float4 xv = { xa.x + xb.x, xa.y + xb.y, xa.z + xb.z, xa.w + xb.w };
    float s  = xv.x + xv.y + xv.z + xv.w;
    float sq = xv.x * xv.x + xv.y * xv.y + xv.z * xv.z + xv.w * xv.w;
    #pragma unroll
    for (int o = 32; o > 0; o >>= 1) {
        s  += __shfl_xor(s, o);
        sq += __shfl_xor(sq, o);
    }
    __shared__ float rs[2], rq[2];
    int wid = t >> 6;
    if ((t & 63) == 0) { rs[wid] = s; rq[wid] = sq; }
    __syncthreads();
    s = rs[0] + rs[1]; sq = rq[0] + rq[1];
    float mu   = s * (1.0f / 512.0f);
    float var  = sq * (1.0f / 512.0f) - mu * mu;
    float rstd = rsqrtf(var + 1e-5f);
    float4 gv = ((const float4*)g)[t];
    float4 bv = ((const float4*)bb)[t];
    float4 y = { (xv.x - mu) * rstd * gv.x + bv.x,
                 (xv.y - mu) * rstd * gv.y + bv.y,
                 (xv.z - mu) * rstd * gv.z + bv.z,
                 (xv.w - mu) * rstd * gv.w + bv.w };
    if (WF32) ((float4*)of)[(long)row * 128 + t] = y;
    bf16x4 yb = { (bf16)y.x, (bf16)y.y, (bf16)y.z, (bf16)y.w };
    ((bf16x4*)ob)[(long)row * 128 + t] = yb;
}

// ---------------------------------------------------------------- causal softmax
__global__ void softmax_causal(const float* __restrict__ sc, bf16* __restrict__ pr) {
    int row = blockIdx.x;            // 8192
    int z = row >> 11, q = row & 2047;
    const float* srow = sc + ((long)z * 2048 + q) * 2048;
    bf16*        prow = pr + ((long)z * 2048 + q) * 2048;
    int t = threadIdx.x;             // 256, each handles 8 cols
    float v[8];
    int c0 = t * 8;
    if (t <= (q >> 3)) {
        float4 v0 = ((const float4*)srow)[t * 2];
        float4 v1 = ((const float4*)srow)[t * 2 + 1];
        v[0] = v0.x; v[1] = v0.y; v[2] = v0.z; v[3] = v0.w;
        v[4] = v1.x; v[5] = v1.y; v[6] = v1.z; v[7] = v1.w;
    } else {
        #pragma unroll
        for (int j = 0; j < 8; j++) v[j] = -1e30f;
    }
    float mx = -1e30f;
    #pragma unroll
    for (int j = 0; j < 8; j++) {
        if (c0 + j > q) v[j] = -1e30f;
        mx = fmaxf(mx, v[j]);
    }
    int lane = t & 63, wid = t >> 6;
    #pragma unroll
    for (int o = 32; o > 0; o >>= 1) mx = fmaxf(mx, __shfl_xor(mx, o));
    __shared__ float redm[4], reds[4];
    if (lane == 0) redm[wid] = mx;
    __syncthreads();
    mx = fmaxf(fmaxf(redm[0], redm[1]), fmaxf(redm[2], redm[3]));
    float p[8]; float sum = 0.f;
    #pragma unroll
    for (int j = 0; j < 8; j++) {
        p[j] = (c0 + j <= q) ? __expf(v[j] - mx) : 0.f;
        sum += p[j];
    }
    #pragma unroll
    for (int o = 32; o > 0; o >>= 1) sum += __shfl_xor(sum, o);
    if (lane == 0) reds[wid] = sum;
    __syncthreads();
    sum = reds[0] + reds[1] + reds[2] + reds[3];
    float inv = 1.0f / sum;
    int wlim = ((q >> 7) + 1) * 128;             // causal 128-block boundary
    if (c0 < wlim) {
        bf16x8 o;
        #pragma unroll
        for (int j = 0; j < 8; j++) o[j] = (bf16)(p[j] * inv);
        *(bf16x8*)&prow[c0] = o;
    }
}

// ---------------------------------------------------------------- epilogue tags
enum { EPI_F32 = 0, EPI_BF16 = 1, EPI_VT = 2, EPI_BIAS_RELU_BF16 = 3, EPI_BIAS_F32 = 4,
       EPI_QKV = 5, EPI_BIAS_F32_NT = 6 };
enum { ZB_BATCH = 0 };

// ---------------------------------------------------------------- 128^2 GEMM (proven)
// 32 KiB LDS + ~120 VGPR -> up to 4 co-resident 4-wave blocks/CU. At grids
// >256 blocks, cross-block overlap gives the proven ~912 TF machine rate;
// this beats the 256^2 8-phase whenever the grid can't exceed 1 block/CU.
template<int EPI, bool CAUSAL_SKIP, bool CAUSAL_K, bool XCD, int ZMODE>
__global__ __launch_bounds__(256)
void gemm_bt(const bf16* __restrict__ A, const bf16* __restrict__ B,
             float* __restrict__ Cf, bf16* __restrict__ Cb,
             const float* __restrict__ bias, float scale,
             int M, int N, int K, int Krow, long sA, long sB, long sC) {
    int br, bc;
    if (XCD) {
        int nwg = gridDim.x * gridDim.y;         // caller ensures %8==0
        int lin = blockIdx.y * gridDim.x + blockIdx.x;
        lin = (lin & 7) * (nwg >> 3) + (lin >> 3);
        br = lin / gridDim.x; bc = lin - br * gridDim.x;
    } else { br = blockIdx.y; bc = blockIdx.x; }
    int z = blockIdx.z;
    A += (long)z * sA; B += (long)z * sB; Cf += (long)z * sC;
    if (CAUSAL_SKIP && bc > br) return;
    int Kext = CAUSAL_K ? min(K, (br + 1) * 128) : K;
    __shared__ bf16 As[128 * 64];
    __shared__ bf16 Bs[128 * 64];
    int tid = threadIdx.x;
    int lane = tid & 63, wid = tid >> 6;
    int wm = (wid >> 1) * 64, wn = (wid & 1) * 64;
    f32x4 acc[4][4] = {};
    int rowA0 = br * 128, colB0 = bc * 128;
    int rsub = lane >> 3;
    int csub = ((lane & 7) ^ rsub) * 8;            // pre-swizzled source col
    int rdsw = (lane & 7) * 8;                     // read-side XOR
    for (int kt = 0; kt < Kext; kt += 64) {
        const bf16* Ag = A + (long)rowA0 * Krow + kt;
        const bf16* Bg = B + (long)colB0 * Krow + kt;
        #pragma unroll
        for (int i = 0; i < 4; i++) {
            int seg = wid * 4 + i;
            int r = seg * 8 + rsub;
            gload_lds16(&Ag[(long)r * Krow + csub], &As[seg * 512]);
            gload_lds16(&Bg[(long)r * Krow + csub], &Bs[seg * 512]);
        }
        __syncthreads();
        #pragma unroll
        for (int kk = 0; kk < 2; kk++) {
            bf16x8 af[4], bfr[4];
            int ko = (kk * 32 + (lane >> 4) * 8) ^ rdsw;
            #pragma unroll
            for (int m = 0; m < 4; m++) af[m]  = *(const bf16x8*)&As[(wm + m * 16 + (lane & 15)) * 64 + ko];
            #pragma unroll
            for (int n = 0; n < 4; n++) bfr[n] = *(const bf16x8*)&Bs[(wn + n * 16 + (lane & 15)) * 64 + ko];
            #pragma unroll
            for (int m = 0; m < 4; m++)
                #pragma unroll
                for (int n = 0; n < 4; n++)
                    acc[m][n] = __builtin_amdgcn_mfma_f32_16x16x32_bf16(af[m], bfr[n], acc[m][n], 0, 0, 0);
        }
        __syncthreads();
    }
    if constexpr (EPI == EPI_QKV) {
        // N=1536; 128-col tiles are region-uniform: colB0/512 = 0:Q 1:K 2:V.
        // Cb = qb; kb = qb + 8192*512; vt = qb + 2*8192*512 (contiguous ws).
        int region = colB0 >> 9;
        if (region < 2) {
            bf16* dst = Cb + (long)region * (8192L * 512);
            int cb0 = (colB0 & 511) + wn;
            #pragma unroll
            for (int m = 0; m < 4; m++)
                #pragma unroll
                for (int n = 0; n < 4; n++)
                    #pragma unroll
                    for (int j = 0; j < 4; j++) {
                        long row = rowA0 + wm + m * 16 + (lane >> 4) * 4 + j;
                        int c = cb0 + n * 16 + (lane & 15);
                        dst[row * 512 + c] = (bf16)acc[m][n][j];
                    }
        } else {
            bf16* vtb = Cb + 2L * 8192 * 512;
            int cb0 = (colB0 - 1024) + wn;
            #pragma unroll
            for (int m = 0; m < 4; m++)
                #pragma unroll
                for (int n = 0; n < 4; n++) {
                    long k0 = rowA0 + wm + m * 16 + (lane >> 4) * 4;
                    long b = k0 >> 11, k = k0 & 2047;
                    int c = cb0 + n * 16 + (lane & 15);
                    bf16x4 pk = { (bf16)acc[m][n][0], (bf16)acc[m][n][1],
                                  (bf16)acc[m][n][2], (bf16)acc[m][n][3] };
                    *(bf16x4*)&vtb[(b * 512 + c) * 2048 + k] = pk;
                }
        }
    } else {
        #pragma unroll
        for (int m = 0; m < 4; m++) {
            #pragma unroll
            for (int n = 0; n < 4; n++) {
                #pragma unroll
                for (int j = 0; j < 4; j++) {
                    int row = rowA0 + wm + m * 16 + (lane >> 4) * 4 + j;
                    int col = colB0 + wn + n * 16 + (lane & 15);
                    float v = acc[m][n][j];
                    if (EPI == EPI_F32) {
                        Cf[(long)row * N + col] = v;    // z-offset already applied
                    } else if (EPI == EPI_BF16) {
                        Cb[(long)row * N + col] = (bf16)(v * scale);
                    } else if (EPI == EPI_VT) {
                        int b = row >> 11, k = row & 2047;
                        Cb[((long)b * 512 + col) * 2048 + k] = (bf16)v;
                    } else if (EPI == EPI_BIAS_RELU_BF16) {
                        float y = fmaxf(v + bias[col], 0.0f);
                        Cb[(long)row * N + col] = (bf16)y;
                    } else if (EPI == EPI_BIAS_F32) {
                        Cf[(long)row * N + col] = v + bias[col];
                    }
                }
            }
        }
    }
}

// ---------------------------------------------------------------- vocab GEMM: 128^2 tile,
// BK=64 double-buffered, 256 thr (4 waves, per-wave 64x64), counted vmcnt.
// 64 KiB LDS + ~120 VGPR -> TWO co-resident blocks/CU. Column-band order
// (BANDB bc-tiles per band) + XCD swizzle keeps the concurrent B slice
// L2-resident; NT stores keep the 1.05 GB output stream out of L2.
template<int BANDB>
__global__ __launch_bounds__(256)
void gemm128v(const bf16* __restrict__ A, const bf16* __restrict__ B,
              float* __restrict__ C, const float* __restrict__ bias,
              int N, int K) {
    const int NBR = 64;                            // 8192/128 row-tiles
    const int NT  = 8;                             // K=512 / 64
    int nwg = gridDim.x;                           // 16000 (%8==0)
    int lin = blockIdx.x;
    lin = (lin & 7) * (nwg >> 3) + (lin >> 3);     // XCD-contiguous chunks
    int per = BANDB * NBR;
    int band = lin / per, w2 = lin - band * per;
    int br = w2 / BANDB, bc = band * BANDB + (w2 - br * BANDB);

    __shared__ bf16 lds[2][2][128 * 64];           // 64 KiB -> 2 blocks/CU
    int tid = threadIdx.x;
    int lane = tid & 63, wid = tid >> 6;
    int wm = (wid >> 1) * 64, wn = (wid & 1) * 64;
    int rsub = lane >> 3;
    int csub = ((lane & 7) ^ rsub) * 8;            // pre-swizzled source col
    int rdsw = (lane & 7) * 8;                     // read-side XOR
    long rowA0 = (long)br * 128, colB0 = (long)bc * 128;
    const bf16* Abase = A + rowA0 * K;
    const bf16* Bbase = B + colB0 * K;
    f32x4 acc[4][4] = {};

    auto stage = [&](int t) {                      // 8 VMEM issues/thread
        int buf = t & 1;
        const bf16* Ag = Abase + t * 64;
        const bf16* Bg = Bbase + t * 64;
        #pragma unroll
        for (int i = 0; i < 4; i++) {
            int seg = wid * 4 + i;                 // 0..15
            long r = seg * 8 + rsub;
            gload_lds16(&Ag[r * K + csub], &lds[buf][0][seg * 512]);
        }
        #pragma unroll
        for (int i = 0; i < 4; i++) {
            int seg = wid * 4 + i;
            long r = seg * 8 + rsub;
            gload_lds16(&Bg[r * K + csub], &lds[buf][1][seg * 512]);
        }
    };

    stage(0);
    stage(1);

    for (int t = 0; t < NT; t++) {
        int buf = t & 1;
        if (t == NT - 1) asm volatile("s_waitcnt vmcnt(0)" ::: "memory");
        else             asm volatile("s_waitcnt vmcnt(8)" ::: "memory");
        __builtin_amdgcn_s_barrier();              // tile-t data visible
        const bf16* As = lds[buf][0];
        const bf16* Bs = lds[buf][1];
        __builtin_amdgcn_s_setprio(1);
        #pragma unroll
        for (int kk = 0; kk < 2; kk++) {
            bf16x8 af[4], bfr[4];
            int ko = (kk * 32 + (lane >> 4) * 8) ^ rdsw;
            #pragma unroll
            for (int m = 0; m < 4; m++) af[m]  = *(const bf16x8*)&As[(wm + m * 16 + (lane & 15)) * 64 + ko];
            #pragma unroll
            for (int n = 0; n < 4; n++) bfr[n] = *(const bf16x8*)&Bs[(wn + n * 16 + (lane & 15)) * 64 + ko];
            #pragma unroll
            for (int m = 0; m < 4; m++)
                #pragma unroll
                for (int n = 0; n < 4; n++)
                    acc[m][n] = __builtin_amdgcn_mfma_f32_16x16x32_bf16(af[m], bfr[n], acc[m][n], 0, 0, 0);
        }
        __builtin_amdgcn_s_setprio(0);
        asm volatile("s_waitcnt lgkmcnt(0)" ::: "memory"); // my buf reads done
        __builtin_amdgcn_sched_barrier(0);
        __builtin_amdgcn_s_barrier();              // ALL waves done reading buf
        if (t + 2 < NT) stage(t + 2);              // overwrite buf
    }

    #pragma unroll
    for (int m = 0; m < 4; m++) {
        #pragma unroll
        for (int n = 0; n < 4; n++) {
            int col = (int)colB0 + wn + n * 16 + (lane & 15);
            float bcol = bias[col];
            #pragma unroll
            for (int j = 0; j < 4; j++) {
                long row = rowA0 + wm + m * 16 + (lane >> 4) * 4 + j;
                __builtin_nontemporal_store(acc[m][n][j] + bcol, &C[row * N + col]);
            }
        }
    }
}

// ---------------------------------------------------------------- launch
extern "C" void kernel_launch(void* const* d_in, const int* in_sizes, int n_in,
                              void* d_out, int out_size, void* d_ws, size_t ws_size,
                              hipStream_t stream) {
    const int*   x       = (const int*)d_in[0];
    const float* word_emb = (const float*)d_in[1];
    const float* pos_emb  = (const float*)d_in[2];
    const float* Wq = (const float*)d_in[3];
    const float* Wk = (const float*)d_in[4];
    const float* Wv = (const float*)d_in[5];
    const float* g1 = (const float*)d_in[6];
    const float* b1 = (const float*)d_in[7];
    const float* w_ffn1 = (const float*)d_in[8];
    const float* b_ffn1 = (const float*)d_in[9];
    const float* w_ffn2 = (const float*)d_in[10];
    const float* b_ffn2 = (const float*)d_in[11];
    const float* g2 = (const float*)d_in[12];
    const float* b2 = (const float*)d_in[13];
    const float* w_vocab = (const float*)d_in[14];
    const float* b_vocab = (const float*)d_in[15];
    float* out = (float*)d_out;

    char* w = (char*)d_ws;
    auto alloc = [&](size_t bytes) { char* p = w; w += (bytes + 255) & ~255ULL; return p; };
    // NOTE: wqb/wkb/wvb must stay contiguous ([1536 x 512] fused weight);
    //       qb/kb/vt must stay contiguous (EPI_QKV writes all three off qb).
    bf16* wqb   = (bf16*)alloc(512 * 512 * 2);
    bf16* wkb   = (bf16*)alloc(512 * 512 * 2);
    bf16* wvb   = (bf16*)alloc(512 * 512 * 2);
    bf16* w1b   = (bf16*)alloc(2048 * 512 * 2);
    bf16* w2b   = (bf16*)alloc(512 * 2048 * 2);
    bf16* wvocb = (bf16*)alloc((size_t)32000 * 512 * 2);
    float* embf = (float*)alloc((size_t)8192 * 512 * 4);
    bf16* embb  = (bf16*)alloc((size_t)8192 * 512 * 2);   // also final_b (aliased)
    bf16* qb    = (bf16*)alloc((size_t)8192 * 512 * 2);
    bf16* kb    = (bf16*)alloc((size_t)8192 * 512 * 2);   // also out1_b (aliased)
    bf16* vt    = (bf16*)alloc((size_t)8192 * 512 * 2);
    float* scores = (float*)alloc((size_t)4 * 2048 * 2048 * 4); // also ffn1_b (aliased)
    bf16* probs = (bf16*)alloc((size_t)4 * 2048 * 2048 * 2);
    float* ctx  = (float*)alloc((size_t)8192 * 512 * 4);
    float* out1f = (float*)alloc((size_t)8192 * 512 * 4);
    float* ffn2f = (float*)alloc((size_t)8192 * 512 * 4);
    bf16* ffn1b = (bf16*)scores;   // alias: scores dead after softmax
    bf16* out1b = kb;              // alias: kb dead after scores GEMM
    bf16* finalb = embb;           // alias: embb dead after QKV GEMM

    const float qscale = 0.044194173824159216f; // 1/sqrt(512)

    // one launch converts all six weight tensors (Wq pre-scaled by 1/sqrt(d_k))
    CvtArgs ca;
    ca.src[0] = Wq;      ca.dst[0] = wqb;   ca.n4[0] = 512 * 512 / 4;          ca.scale[0] = qscale;
    ca.src[1] = Wk;      ca.dst[1] = wkb;   ca.n4[1] = 512 * 512 / 4;          ca.scale[1] = 1.0f;
    ca.src[2] = Wv;      ca.dst[2] = wvb;   ca.n4[2] = 512 * 512 / 4;          ca.scale[2] = 1.0f;
    ca.src[3] = w_ffn1;  ca.dst[3] = w1b;   ca.n4[3] = 2048 * 512 / 4;         ca.scale[3] = 1.0f;
    ca.src[4] = w_ffn2;  ca.dst[4] = w2b;   ca.n4[4] = 512 * 2048 / 4;         ca.scale[4] = 1.0f;
    ca.src[5] = w_vocab; ca.dst[5] = wvocb; ca.n4[5] = (long)32000 * 512 / 4;  ca.scale[5] = 1.0f;
    cvt_all<<<dim3(256, 6), 256, 0, stream>>>(ca);

    embed_kernel<<<8192, 128, 0, stream>>>(x, word_emb, pos_emb, embf, embb);

    // fused Q|K|V projection: 128^2 tiles, 768 blocks = 3/CU (vs 192 = 0.75/CU
    // at 256^2): cross-block overlap -> ~912 TF machine rate.
    gemm_bt<EPI_QKV, false, false, true, ZB_BATCH><<<dim3(12, 64, 1), 256, 0, stream>>>(
        embb, wqb, nullptr, qb, nullptr, 1.0f, 8192, 1536, 512, 512, 0, 0, 0);

    // scores = Q @ K^T: 128^2 tiles, 544 active blocks (~2.1/CU), causal skip.
    gemm_bt<EPI_F32, true, false, false, ZB_BATCH><<<dim3(16, 16, 4), 256, 0, stream>>>(
        qb, kb, scores, nullptr, nullptr, 1.0f, 2048, 2048, 512, 512,
        (long)2048 * 512, (long)2048 * 512, (long)2048 * 2048);

    softmax_causal<<<8192, 256, 0, stream>>>(scores, probs);

    // context = P @ V (B operand = V^T, batched, causal K-limit)
    gemm_bt<EPI_F32, false, true, false, ZB_BATCH><<<dim3(4, 16, 4), 256, 0, stream>>>(
        probs, vt, ctx, nullptr, nullptr, 1.0f, 2048, 512, 2048, 2048,
        (long)2048 * 2048, (long)512 * 2048, (long)2048 * 512);

    ln_kernel<true><<<8192, 128, 0, stream>>>(embf, ctx, g1, b1, out1f, out1b);

    // ffn1 = relu(out1 @ W1^T + b1): 128^2 tiles, 1024 blocks = 4/CU.
    gemm_bt<EPI_BIAS_RELU_BF16, false, false, true, ZB_BATCH><<<dim3(16, 64, 1), 256, 0, stream>>>(
        out1b, w1b, nullptr, ffn1b, b_ffn1, 1.0f, 8192, 2048, 512, 512, 0, 0, 0);

    // ffn2 = ffn1 @ W2^T + b2  (N=512 -> 128^2)
    gemm_bt<EPI_BIAS_F32, false, false, false, ZB_BATCH><<<dim3(4, 64, 1), 256, 0, stream>>>(
        ffn1b, w2b, ffn2f, nullptr, b_ffn2, 1.0f, 8192, 512, 2048, 2048, 0, 0, 0);

    ln_kernel<false><<<8192, 128, 0, stream>>>(out1f, ffn2f, g2, b2, nullptr, finalb);

    // logits = final @ w_vocab^T + b_vocab  -- 128^2 double-buffered pipeline,
    // 2 blocks/CU, 25 bands of 10 bc-tiles, NT stores (R8 proven).
    gemm128v<10><<<16000, 256, 0, stream>>>(finalb, wvocb, out, b_vocab, 32000, 512);
}

// Round 10
// 535.503 us; speedup vs baseline: 1.0474x; 1.0474x over previous
//
#include <hip/hip_runtime.h>
#include <hip/hip_bf16.h>

typedef __bf16 bf16;
typedef __attribute__((ext_vector_type(4))) __bf16 bf16x4;
typedef __attribute__((ext_vector_type(8))) __bf16 bf16x8;
typedef __attribute__((ext_vector_type(4))) float f32x4;

__device__ inline void gload_lds16(const bf16* g, bf16* l) {
    __builtin_amdgcn_global_load_lds(
        (const __attribute__((address_space(1))) void*)g,
        (__attribute__((address_space(3))) void*)l, 16, 0, 0);
}

// ---------------------------------------------------------------- fused conversions
struct CvtArgs {
    const float* src[6];
    bf16* dst[6];
    long n4[6];
    float scale[6];
};
__global__ void cvt_all(CvtArgs a) {
    int j = blockIdx.y;
    const float* __restrict__ src = a.src[j];
    bf16* __restrict__ dst = a.dst[j];
    long n4 = a.n4[j];
    float sc = a.scale[j];
    long i = (long)blockIdx.x * blockDim.x + threadIdx.x;
    long stride = (long)gridDim.x * blockDim.x;
    for (; i < n4; i += stride) {
        float4 v = ((const float4*)src)[i];
        bf16x4 o = { (bf16)(v.x * sc), (bf16)(v.y * sc), (bf16)(v.z * sc), (bf16)(v.w * sc) };
        ((bf16x4*)dst)[i] = o;
    }
}

// ---------------------------------------------------------------- embedding
__global__ void embed_kernel(const int* __restrict__ x, const float* __restrict__ we,
                             const float* __restrict__ pe, float* __restrict__ emb_f,
                             bf16* __restrict__ emb_b) {
    int row = blockIdx.x;            // 0..8191  (b*2048 + s)
    int c   = threadIdx.x;           // 0..127
    int tok = x[row];
    int s   = row & 2047;
    float4 w = ((const float4*)we)[(long)tok * 128 + c];
    float4 p = ((const float4*)pe)[(long)s * 128 + c];
    float4 e = { w.x + p.x, w.y + p.y, w.z + p.z, w.w + p.w };
    ((float4*)emb_f)[(long)row * 128 + c] = e;
    bf16x4 eb = { (bf16)e.x, (bf16)e.y, (bf16)e.z, (bf16)e.w };
    ((bf16x4*)emb_b)[(long)row * 128 + c] = eb;
}

// ---------------------------------------------------------------- layernorm
// Residual = a + b [+ c] [+ rb(col bias)].
// C3: 0 = no third input, 1 = add c only for rows with (row&2047)>=1024
// (PV split-K chunk-1 coverage), 2 = always add c (ffn2 split-K partials).
template<bool WF32, int C3, bool RBIAS>
__global__ void ln_kernel(const float* __restrict__ a, const float* __restrict__ b,
                          const float* __restrict__ c, const float* __restrict__ rb,
                          const float* __restrict__ g, const float* __restrict__ bb,
                          float* __restrict__ of, bf16* __restrict__ ob) {
    int row = blockIdx.x;            // 8192
    int t   = threadIdx.x;           // 128
    float4 xa = ((const float4*)a)[(long)row * 128 + t];
    float4 xb = ((const float4*)b)[(long)row * 128 + t];
    float4 xv = { xa.x + xb.x, xa.y + xb.y, xa.z + xb.z, xa.w + xb.w };
    if (C3 == 2 || (C3 == 1 && (row & 2047) >= 1024)) {
        float4 xc = ((const float4*)c)[(long)row * 128 + t];
        xv.x += xc.x; xv.y += xc.y; xv.z += xc.z; xv.w += xc.w;
    }
    if (RBIAS) {
        float4 rv = ((const float4*)rb)[t];
        xv.x += rv.x; xv.y += rv.y; xv.z += rv.z; xv.w += rv.w;
    }
    float s  = xv.x + xv.y + xv.z + xv.w;
    float sq = xv.x * xv.x + xv.y * xv.y + xv.z * xv.z + xv.w * xv.w;
    #pragma unroll
    for (int o = 32; o > 0; o >>= 1) {
        s  += __shfl_xor(s, o);
        sq += __shfl_xor(sq, o);
    }
    __shared__ float rs[2], rq[2];
    int wid = t >> 6;
    if ((t & 63) == 0) { rs[wid] = s; rq[wid] = sq; }
    __syncthreads();
    s = rs[0] + rs[1]; sq = rq[0] + rq[1];
    float mu   = s * (1.0f / 512.0f);
    float var  = sq * (1.0f / 512.0f) - mu * mu;
    float rstd = rsqrtf(var + 1e-5f);
    float4 gv = ((const float4*)g)[t];
    float4 bv = ((const float4*)bb)[t];
    float4 y = { (xv.x - mu) * rstd * gv.x + bv.x,
                 (xv.y - mu) * rstd * gv.y + bv.y,
                 (xv.z - mu) * rstd * gv.z + bv.z,
                 (xv.w - mu) * rstd * gv.w + bv.w };
    if (WF32) ((float4*)of)[(long)row * 128 + t] = y;
    bf16x4 yb = { (bf16)y.x, (bf16)y.y, (bf16)y.z, (bf16)y.w };
    ((bf16x4*)ob)[(long)row * 128 + t] = yb;
}

// ---------------------------------------------------------------- causal softmax
__global__ void softmax_causal(const float* __restrict__ sc, bf16* __restrict__ pr) {
    int row = blockIdx.x;            // 8192
    int z = row >> 11, q = row & 2047;
    const float* srow = sc + ((long)z * 2048 + q) * 2048;
    bf16*        prow = pr + ((long)z * 2048 + q) * 2048;
    int t = threadIdx.x;             // 256, each handles 8 cols
    float v[8];
    int c0 = t * 8;
    if (t <= (q >> 3)) {
        float4 v0 = ((const float4*)srow)[t * 2];
        float4 v1 = ((const float4*)srow)[t * 2 + 1];
        v[0] = v0.x; v[1] = v0.y; v[2] = v0.z; v[3] = v0.w;
        v[4] = v1.x; v[5] = v1.y; v[6] = v1.z; v[7] = v1.w;
    } else {
        #pragma unroll
        for (int j = 0; j < 8; j++) v[j] = -1e30f;
    }
    float mx = -1e30f;
    #pragma unroll
    for (int j = 0; j < 8; j++) {
        if (c0 + j > q) v[j] = -1e30f;
        mx = fmaxf(mx, v[j]);
    }
    int lane = t & 63, wid = t >> 6;
    #pragma unroll
    for (int o = 32; o > 0; o >>= 1) mx = fmaxf(mx, __shfl_xor(mx, o));
    __shared__ float redm[4], reds[4];
    if (lane == 0) redm[wid] = mx;
    __syncthreads();
    mx = fmaxf(fmaxf(redm[0], redm[1]), fmaxf(redm[2], redm[3]));
    float p[8]; float sum = 0.f;
    #pragma unroll
    for (int j = 0; j < 8; j++) {
        p[j] = (c0 + j <= q) ? __expf(v[j] - mx) : 0.f;
        sum += p[j];
    }
    #pragma unroll
    for (int o = 32; o > 0; o >>= 1) sum += __shfl_xor(sum, o);
    if (lane == 0) reds[wid] = sum;
    __syncthreads();
    sum = reds[0] + reds[1] + reds[2] + reds[3];
    float inv = 1.0f / sum;
    int wlim = ((q >> 7) + 1) * 128;             // causal 128-block boundary
    if (c0 < wlim) {
        bf16x8 o;
        #pragma unroll
        for (int j = 0; j < 8; j++) o[j] = (bf16)(p[j] * inv);
        *(bf16x8*)&prow[c0] = o;
    }
}

// ---------------------------------------------------------------- epilogue tags
enum { EPI_F32 = 0, EPI_BF16 = 1, EPI_VT = 2, EPI_BIAS_RELU_BF16 = 3, EPI_BIAS_F32 = 4,
       EPI_QKV = 5, EPI_BIAS_F32_NT = 6 };
enum { ZB_BATCH = 0, ZB_PV = 1 };

// ---------------------------------------------------------------- 128^2 GEMM (proven)
// ZB_BATCH: z = batch (or K-chunk); A/B/Cf shifted by z*sA/sB/sC elements.
// ZB_PV   : z = batch*2 + chunk. Causal P@V with split-K chunks of 1024:
//           chunk 0 covers k in [0,1024), chunk 1 covers [1024, keff).
//           Cf base for chunk 1 is Cf + 8192*512 (pv1 buffer adjacent to pv0);
//           blocks whose causal keff <= lo exit early (block-uniform).
template<int EPI, bool CAUSAL_SKIP, bool CAUSAL_K, bool XCD, int ZMODE>
__global__ __launch_bounds__(256)
void gemm_bt(const bf16* __restrict__ A, const bf16* __restrict__ B,
             float* __restrict__ Cf, bf16* __restrict__ Cb,
             const float* __restrict__ bias, float scale,
             int M, int N, int K, int Krow, long sA, long sB, long sC) {
    int br, bc;
    if (XCD) {
        int nwg = gridDim.x * gridDim.y;         // caller ensures %8==0
        int lin = blockIdx.y * gridDim.x + blockIdx.x;
        lin = (lin & 7) * (nwg >> 3) + (lin >> 3);
        br = lin / gridDim.x; bc = lin - br * gridDim.x;
    } else { br = blockIdx.y; bc = blockIdx.x; }
    int z = blockIdx.z;
    int Kext = K;
    if (ZMODE == ZB_BATCH) {
        A += (long)z * sA; B += (long)z * sB; Cf += (long)z * sC;
    } else if (ZMODE == ZB_PV) {
        int batch = z >> 1, chunk = z & 1;
        A += (long)batch * sA; B += (long)batch * sB;
        Cf += (long)chunk * (8192L * 512) + (long)batch * sC;
        int keff = min(K, (br + 1) * 128);
        int lo = chunk * 1024;
        if (keff <= lo) return;                  // block-uniform early exit
        A += lo; B += lo;
        Kext = min(keff, lo + 1024) - lo;
    }
    if (CAUSAL_SKIP && bc > br) return;
    if (CAUSAL_K) Kext = min(Kext, (br + 1) * 128);
    __shared__ bf16 As[128 * 64];
    __shared__ bf16 Bs[128 * 64];
    int tid = threadIdx.x;
    int lane = tid & 63, wid = tid >> 6;
    int wm = (wid >> 1) * 64, wn = (wid & 1) * 64;
    f32x4 acc[4][4] = {};
    int rowA0 = br * 128, colB0 = bc * 128;
    int rsub = lane >> 3;
    int csub = ((lane & 7) ^ rsub) * 8;            // pre-swizzled source col
    int rdsw = (lane & 7) * 8;                     // read-side XOR
    for (int kt = 0; kt < Kext; kt += 64) {
        const bf16* Ag = A + (long)rowA0 * Krow + kt;
        const bf16* Bg = B + (long)colB0 * Krow + kt;
        #pragma unroll
        for (int i = 0; i < 4; i++) {
            int seg = wid * 4 + i;
            int r = seg * 8 + rsub;
            gload_lds16(&Ag[(long)r * Krow + csub], &As[seg * 512]);
            gload_lds16(&Bg[(long)r * Krow + csub], &Bs[seg * 512]);
        }
        __syncthreads();
        #pragma unroll
        for (int kk = 0; kk < 2; kk++) {
            bf16x8 af[4], bfr[4];
            int ko = (kk * 32 + (lane >> 4) * 8) ^ rdsw;
            #pragma unroll
            for (int m = 0; m < 4; m++) af[m]  = *(const bf16x8*)&As[(wm + m * 16 + (lane & 15)) * 64 + ko];
            #pragma unroll
            for (int n = 0; n < 4; n++) bfr[n] = *(const bf16x8*)&Bs[(wn + n * 16 + (lane & 15)) * 64 + ko];
            #pragma unroll
            for (int m = 0; m < 4; m++)
                #pragma unroll
                for (int n = 0; n < 4; n++)
                    acc[m][n] = __builtin_amdgcn_mfma_f32_16x16x32_bf16(af[m], bfr[n], acc[m][n], 0, 0, 0);
        }
        __syncthreads();
    }
    #pragma unroll
    for (int m = 0; m < 4; m++) {
        #pragma unroll
        for (int n = 0; n < 4; n++) {
            #pragma unroll
            for (int j = 0; j < 4; j++) {
                int row = rowA0 + wm + m * 16 + (lane >> 4) * 4 + j;
                int col = colB0 + wn + n * 16 + (lane & 15);
                float v = acc[m][n][j];
                if (EPI == EPI_F32) {
                    Cf[(long)row * N + col] = v;        // z-offsets already applied
                } else if (EPI == EPI_BF16) {
                    Cb[(long)row * N + col] = (bf16)(v * scale);
                } else if (EPI == EPI_VT) {
                    int b = row >> 11, k = row & 2047;
                    Cb[((long)b * 512 + col) * 2048 + k] = (bf16)v;
                } else if (EPI == EPI_BIAS_RELU_BF16) {
                    float y = fmaxf(v + bias[col], 0.0f);
                    Cb[(long)row * N + col] = (bf16)y;
                } else if (EPI == EPI_BIAS_F32) {
                    Cf[(long)row * N + col] = v + bias[col];
                }
            }
        }
    }
}

// ---------------------------------------------------------------- 256^2 deep-pipeline GEMM (BK=64)
// BANDW > 0: column-band tile order (see R6/R7 notes).
template<int EPI, bool XCD, bool CSKIP, int BANDW, int NT>
__global__ __launch_bounds__(512)
void gemm256(const bf16* __restrict__ A, const bf16* __restrict__ B,
             float* __restrict__ Cf, bf16* __restrict__ Cb,
             const float* __restrict__ bias, int N, int K,
             long sA, long sB, long sC) {
    int br, bc;
    if (XCD) {
        int nwg = gridDim.x * gridDim.y;          // caller ensures %8==0
        int lin = blockIdx.y * gridDim.x + blockIdx.x;
        lin = (lin & 7) * (nwg >> 3) + (lin >> 3);
        if (BANDW > 0) {
            int per = BANDW * gridDim.y;          // blocks per band
            int band = lin / per, w2 = lin - band * per;
            br = w2 / BANDW; bc = band * BANDW + (w2 - br * BANDW);
        } else {
            br = lin / gridDim.x; bc = lin - br * gridDim.x;
        }
    } else { br = blockIdx.y; bc = blockIdx.x; }
    if (CSKIP && bc > br) return;                 // causal skip at 256-tile granularity
    int z = blockIdx.z;
    A  += (long)z * sA;
    B  += (long)z * sB;
    Cf += (long)z * sC;
    __shared__ bf16 lds[2][2][256 * 64];          // [buf][A/B] = 128 KiB
    int tid = threadIdx.x;
    int lane = tid & 63, wid = tid >> 6;
    int wm2 = wid >> 2, wn4 = wid & 3;
    long rowA0 = (long)br * 256, colB0 = (long)bc * 256;
    int rsub = lane >> 3;
    int csw  = ((lane & 7) ^ rsub) * 8;           // pre-swizzled source col
    int l15 = lane & 15;
    int rdxor = (lane & 7) << 3;
    int kbase = (lane >> 4) * 8;
    const bf16* Abase = A + rowA0 * K;
    const bf16* Bbase = B + colB0 * K;
    f32x4 acc[8][4] = {};

    auto stage = [&](int t) {
        int buf = t & 1;
        const bf16* Ag = Abase + t * 64;
        const bf16* Bg = Bbase + t * 64;
        #pragma unroll
        for (int i = 0; i < 4; i++) {
            int seg = wid * 4 + i;                // 0..31
            long r = seg * 8 + rsub;
            gload_lds16(&Ag[r * K + csw], &lds[buf][0][seg * 512]);
        }
        #pragma unroll
        for (int i = 0; i < 4; i++) {
            int seg = wid * 4 + i;
            long r = seg * 8 + rsub;
            gload_lds16(&Bg[r * K + csw], &lds[buf][1][seg * 512]);
        }
    };

    stage(0);
    stage(1);

    for (int t = 0; t < NT; t++) {
        int buf = t & 1;
        if (t == NT - 1) asm volatile("s_waitcnt vmcnt(0)" ::: "memory");
        else             asm volatile("s_waitcnt vmcnt(8)" ::: "memory");
        __builtin_amdgcn_s_barrier();             // everyone's tile-t data visible
        const bf16* As = lds[buf][0];
        const bf16* Bs = lds[buf][1];
        bf16x8 bfr[2][4], af[2][4];
        #pragma unroll
        for (int kk = 0; kk < 2; kk++)
            #pragma unroll
            for (int n = 0; n < 4; n++) {
                int r = wn4 * 64 + n * 16 + l15;
                bfr[kk][n] = *(const bf16x8*)&Bs[r * 64 + ((kk * 32 + kbase) ^ rdxor)];
            }
        #pragma unroll
        for (int kk = 0; kk < 2; kk++)
            #pragma unroll
            for (int m = 0; m < 4; m++) {
                int r = wm2 * 128 + m * 16 + l15;
                af[kk][m] = *(const bf16x8*)&As[r * 64 + ((kk * 32 + kbase) ^ rdxor)];
            }
        __builtin_amdgcn_s_setprio(1);
        #pragma unroll
        for (int kk = 0; kk < 2; kk++)
            #pragma unroll
            for (int m = 0; m < 4; m++)
                #pragma unroll
                for (int n = 0; n < 4; n++)
                    acc[m][n] = __builtin_amdgcn_mfma_f32_16x16x32_bf16(af[kk][m], bfr[kk][n], acc[m][n], 0, 0, 0);
        __builtin_amdgcn_s_setprio(0);
        // second half of A rows
        #pragma unroll
        for (int kk = 0; kk < 2; kk++)
            #pragma unroll
            for (int m = 0; m < 4; m++) {
                int r = wm2 * 128 + 64 + m * 16 + l15;
                af[kk][m] = *(const bf16x8*)&As[r * 64 + ((kk * 32 + kbase) ^ rdxor)];
            }
        asm volatile("s_waitcnt lgkmcnt(0)" ::: "memory"); // all my buf reads done
        __builtin_amdgcn_sched_barrier(0);
        __builtin_amdgcn_s_barrier();             // ALL waves done reading buf
        if (t + 2 < NT) stage(t + 2);             // overwrite buf; flies across iters
        __builtin_amdgcn_s_setprio(1);
        #pragma unroll
        for (int kk = 0; kk < 2; kk++)
            #pragma unroll
            for (int m = 0; m < 4; m++)
                #pragma unroll
                for (int n = 0; n < 4; n++)
                    acc[4 + m][n] = __builtin_amdgcn_mfma_f32_16x16x32_bf16(af[kk][m], bfr[kk][n], acc[4 + m][n], 0, 0, 0);
        __builtin_amdgcn_s_setprio(0);
    }

    if constexpr (EPI == EPI_QKV) {
        // N=1536; 256-col panels are block-uniform: 0-1=Q, 2-3=K, 4-5=V.
        int region = (int)(colB0 >> 9);           // 0=Q, 1=K, 2=V
        if (region < 2) {
            bf16* dst = Cb + (long)region * (8192L * 512);
            int cb = ((int)colB0 & 511) + wn4 * 64;
            #pragma unroll
            for (int m = 0; m < 8; m++)
                #pragma unroll
                for (int n = 0; n < 4; n++)
                    #pragma unroll
                    for (int j = 0; j < 4; j++) {
                        long row = rowA0 + wm2 * 128 + m * 16 + (lane >> 4) * 4 + j;
                        int c = cb + n * 16 + l15;
                        dst[row * 512 + c] = (bf16)acc[m][n][j];
                    }
        } else {
            bf16* vtb = Cb + 2L * 8192 * 512;
            int cb = ((int)colB0 - 1024) + wn4 * 64;
            #pragma unroll
            for (int m = 0; m < 8; m++)
                #pragma unroll
                for (int n = 0; n < 4; n++) {
                    long k0 = rowA0 + wm2 * 128 + m * 16 + (lane >> 4) * 4;
                    long b = k0 >> 11, k = k0 & 2047;
                    int c = cb + n * 16 + l15;
                    bf16x4 pk = { (bf16)acc[m][n][0], (bf16)acc[m][n][1],
                                  (bf16)acc[m][n][2], (bf16)acc[m][n][3] };
                    *(bf16x4*)&vtb[(b * 512 + c) * 2048 + k] = pk;
                }
        }
    } else {
        #pragma unroll
        for (int m = 0; m < 8; m++) {
            #pragma unroll
            for (int n = 0; n < 4; n++) {
                #pragma unroll
                for (int j = 0; j < 4; j++) {
                    long row = rowA0 + wm2 * 128 + m * 16 + (lane >> 4) * 4 + j;
                    long col = colB0 + wn4 * 64 + n * 16 + l15;
                    float v = acc[m][n][j];
                    if (EPI == EPI_BIAS_F32) {
                        Cf[row * N + col] = v + bias[col];
                    } else if (EPI == EPI_BIAS_F32_NT) {
                        __builtin_nontemporal_store(v + bias[col], &Cf[row * N + col]);
                    } else if (EPI == EPI_BIAS_RELU_BF16) {
                        Cb[row * N + col] = (bf16)fmaxf(v + bias[col], 0.0f);
                    } else if (EPI == EPI_F32) {
                        Cf[row * N + col] = v;
                    }
                }
            }
        }
    }
}

// ---------------------------------------------------------------- vocab GEMM (R8 proven)
template<int BANDB>
__global__ __launch_bounds__(256)
void gemm128v(const bf16* __restrict__ A, const bf16* __restrict__ B,
              float* __restrict__ C, const float* __restrict__ bias,
              int N, int K) {
    const int NBR = 64;                            // 8192/128 row-tiles
    const int NT  = 8;                             // K=512 / 64
    int nwg = gridDim.x;                           // 16000 (%8==0)
    int lin = blockIdx.x;
    lin = (lin & 7) * (nwg >> 3) + (lin >> 3);     // XCD-contiguous chunks
    int per = BANDB * NBR;
    int band = lin / per, w2 = lin - band * per;
    int br = w2 / BANDB, bc = band * BANDB + (w2 - br * BANDB);

    __shared__ bf16 lds[2][2][128 * 64];           // 64 KiB -> 2 blocks/CU
    int tid = threadIdx.x;
    int lane = tid & 63, wid = tid >> 6;
    int wm = (wid >> 1) * 64, wn = (wid & 1) * 64;
    int rsub = lane >> 3;
    int csub = ((lane & 7) ^ rsub) * 8;            // pre-swizzled source col
    int rdsw = (lane & 7) * 8;                     // read-side XOR
    long rowA0 = (long)br * 128, colB0 = (long)bc * 128;
    const bf16* Abase = A + rowA0 * K;
    const bf16* Bbase = B + colB0 * K;
    f32x4 acc[4][4] = {};

    auto stage = [&](int t) {                      // 8 VMEM issues/thread
        int buf = t & 1;
        const bf16* Ag = Abase + t * 64;
        const bf16* Bg = Bbase + t * 64;
        #pragma unroll
        for (int i = 0; i < 4; i++) {
            int seg = wid * 4 + i;                 // 0..15
            long r = seg * 8 + rsub;
            gload_lds16(&Ag[r * K + csub], &lds[buf][0][seg * 512]);
        }
        #pragma unroll
        for (int i = 0; i < 4; i++) {
            int seg = wid * 4 + i;
            long r = seg * 8 + rsub;
            gload_lds16(&Bg[r * K + csub], &lds[buf][1][seg * 512]);
        }
    };

    stage(0);
    stage(1);

    for (int t = 0; t < NT; t++) {
        int buf = t & 1;
        if (t == NT - 1) asm volatile("s_waitcnt vmcnt(0)" ::: "memory");
        else             asm volatile("s_waitcnt vmcnt(8)" ::: "memory");
        __builtin_amdgcn_s_barrier();              // tile-t data visible
        const bf16* As = lds[buf][0];
        const bf16* Bs = lds[buf][1];
        __builtin_amdgcn_s_setprio(1);
        #pragma unroll
        for (int kk = 0; kk < 2; kk++) {
            bf16x8 af[4], bfr[4];
            int ko = (kk * 32 + (lane >> 4) * 8) ^ rdsw;
            #pragma unroll
            for (int m = 0; m < 4; m++) af[m]  = *(const bf16x8*)&As[(wm + m * 16 + (lane & 15)) * 64 + ko];
            #pragma unroll
            for (int n = 0; n < 4; n++) bfr[n] = *(const bf16x8*)&Bs[(wn + n * 16 + (lane & 15)) * 64 + ko];
            #pragma unroll
            for (int m = 0; m < 4; m++)
                #pragma unroll
                for (int n = 0; n < 4; n++)
                    acc[m][n] = __builtin_amdgcn_mfma_f32_16x16x32_bf16(af[m], bfr[n], acc[m][n], 0, 0, 0);
        }
        __builtin_amdgcn_s_setprio(0);
        asm volatile("s_waitcnt lgkmcnt(0)" ::: "memory"); // my buf reads done
        __builtin_amdgcn_sched_barrier(0);
        __builtin_amdgcn_s_barrier();              // ALL waves done reading buf
        if (t + 2 < NT) stage(t + 2);              // overwrite buf
    }

    #pragma unroll
    for (int m = 0; m < 4; m++) {
        #pragma unroll
        for (int n = 0; n < 4; n++) {
            int col = (int)colB0 + wn + n * 16 + (lane & 15);
            float bcol = bias[col];
            #pragma unroll
            for (int j = 0; j < 4; j++) {
                long row = rowA0 + wm + m * 16 + (lane >> 4) * 4 + j;
                __builtin_nontemporal_store(acc[m][n][j] + bcol, &C[row * N + col]);
            }
        }
    }
}

// ---------------------------------------------------------------- launch
extern "C" void kernel_launch(void* const* d_in, const int* in_sizes, int n_in,
                              void* d_out, int out_size, void* d_ws, size_t ws_size,
                              hipStream_t stream) {
    const int*   x       = (const int*)d_in[0];
    const float* word_emb = (const float*)d_in[1];
    const float* pos_emb  = (const float*)d_in[2];
    const float* Wq = (const float*)d_in[3];
    const float* Wk = (const float*)d_in[4];
    const float* Wv = (const float*)d_in[5];
    const float* g1 = (const float*)d_in[6];
    const float* b1 = (const float*)d_in[7];
    const float* w_ffn1 = (const float*)d_in[8];
    const float* b_ffn1 = (const float*)d_in[9];
    const float* w_ffn2 = (const float*)d_in[10];
    const float* b_ffn2 = (const float*)d_in[11];
    const float* g2 = (const float*)d_in[12];
    const float* b2 = (const float*)d_in[13];
    const float* w_vocab = (const float*)d_in[14];
    const float* b_vocab = (const float*)d_in[15];
    float* out = (float*)d_out;

    char* w = (char*)d_ws;
    auto alloc = [&](size_t bytes) { char* p = w; w += (bytes + 255) & ~255ULL; return p; };
    // NOTE: wqb/wkb/wvb must stay contiguous ([1536 x 512] fused weight);
    //       qb/kb/vt contiguous (EPI_QKV writes all three off qb);
    //       ctx/pv1 contiguous (ZB_PV chunk offset = 8192*512 floats);
    //       ffn2f/ffn2b contiguous (split-K sC = 8192*512 floats).
    bf16* wqb   = (bf16*)alloc(512 * 512 * 2);
    bf16* wkb   = (bf16*)alloc(512 * 512 * 2);
    bf16* wvb   = (bf16*)alloc(512 * 512 * 2);
    bf16* w1b   = (bf16*)alloc(2048 * 512 * 2);
    bf16* w2b   = (bf16*)alloc(512 * 2048 * 2);
    bf16* wvocb = (bf16*)alloc((size_t)32000 * 512 * 2);
    float* embf = (float*)alloc((size_t)8192 * 512 * 4);
    bf16* embb  = (bf16*)alloc((size_t)8192 * 512 * 2);   // also final_b (aliased)
    bf16* qb    = (bf16*)alloc((size_t)8192 * 512 * 2);
    bf16* kb    = (bf16*)alloc((size_t)8192 * 512 * 2);   // also out1_b (aliased)
    bf16* vt    = (bf16*)alloc((size_t)8192 * 512 * 2);
    float* scores = (float*)alloc((size_t)4 * 2048 * 2048 * 4); // also ffn1_b (aliased)
    bf16* probs = (bf16*)alloc((size_t)4 * 2048 * 2048 * 2);
    float* ctx  = (float*)alloc((size_t)8192 * 512 * 4);  // pv0
    float* pv1  = (float*)alloc((size_t)8192 * 512 * 4);  // pv chunk-1 partial
    float* out1f = (float*)alloc((size_t)8192 * 512 * 4);
    float* ffn2f = (float*)alloc((size_t)8192 * 512 * 4); // ffn2 chunk-0 partial
    float* ffn2b = (float*)alloc((size_t)8192 * 512 * 4); // ffn2 chunk-1 partial
    bf16* ffn1b = (bf16*)scores;   // alias: scores dead after softmax
    bf16* out1b = kb;              // alias: kb dead after scores GEMM
    bf16* finalb = embb;           // alias: embb dead after QKV GEMM

    const float qscale = 0.044194173824159216f; // 1/sqrt(512)

    // one launch converts all six weight tensors (Wq pre-scaled by 1/sqrt(d_k))
    CvtArgs ca;
    ca.src[0] = Wq;      ca.dst[0] = wqb;   ca.n4[0] = 512 * 512 / 4;          ca.scale[0] = qscale;
    ca.src[1] = Wk;      ca.dst[1] = wkb;   ca.n4[1] = 512 * 512 / 4;          ca.scale[1] = 1.0f;
    ca.src[2] = Wv;      ca.dst[2] = wvb;   ca.n4[2] = 512 * 512 / 4;          ca.scale[2] = 1.0f;
    ca.src[3] = w_ffn1;  ca.dst[3] = w1b;   ca.n4[3] = 2048 * 512 / 4;         ca.scale[3] = 1.0f;
    ca.src[4] = w_ffn2;  ca.dst[4] = w2b;   ca.n4[4] = 512 * 2048 / 4;         ca.scale[4] = 1.0f;
    ca.src[5] = w_vocab; ca.dst[5] = wvocb; ca.n4[5] = (long)32000 * 512 / 4;  ca.scale[5] = 1.0f;
    cvt_all<<<dim3(256, 6), 256, 0, stream>>>(ca);

    embed_kernel<<<8192, 128, 0, stream>>>(x, word_emb, pos_emb, embf, embb);

    // fused Q|K|V projection: emb[8192x512] @ Wqkv^T[1536x512] -> qb,kb,vt
    gemm256<EPI_QKV, true, false, 0, 8><<<dim3(6, 32, 1), 512, 0, stream>>>(
        embb, wqb, nullptr, qb, nullptr, 1536, 512, 0, 0, 0);

    // scores = Q @ K^T (batched 256^2 deep pipeline, causal block skip)
    gemm256<EPI_F32, true, true, 0, 8><<<dim3(8, 8, 4), 512, 0, stream>>>(
        qb, kb, scores, nullptr, nullptr, 2048, 512,
        (long)2048 * 512, (long)2048 * 512, (long)2048 * 2048);

    softmax_causal<<<8192, 256, 0, stream>>>(scores, probs);

    // context = P @ V, split-K x2 without atomics: chunk 0 -> ctx (pv0),
    // chunk 1 (rows with causal keff > 1024) -> pv1; summed inside ln1.
    // 384 active blocks (1.5/CU), straggler tail halved to 16 K-steps.
    gemm_bt<EPI_F32, false, false, false, ZB_PV><<<dim3(4, 16, 8), 256, 0, stream>>>(
        probs, vt, ctx, nullptr, nullptr, 1.0f, 2048, 512, 2048, 2048,
        (long)2048 * 2048, (long)512 * 2048, (long)2048 * 512);

    // ln1: residual = embf + pv0 (+ pv1 for rows >= 1024 within each batch)
    ln_kernel<true, 1, false><<<8192, 128, 0, stream>>>(
        embf, ctx, pv1, nullptr, g1, b1, out1f, out1b);

    // ffn1 = relu(out1 @ W1^T + b1)  -- 256^2 deep pipeline
    gemm256<EPI_BIAS_RELU_BF16, true, false, 0, 8><<<dim3(8, 32, 1), 512, 0, stream>>>(
        out1b, w1b, nullptr, ffn1b, b_ffn1, 2048, 512, 0, 0, 0);

    // ffn2 = ffn1 @ W2^T, split-K x2 without atomics: chunk z covers K cols
    // [z*1024, z*1024+1024) -> ffn2f/ffn2b; summed (+b_ffn2) inside ln2.
    // 512 blocks (2/CU) instead of 256 (1/CU).
    gemm_bt<EPI_F32, false, false, false, ZB_BATCH><<<dim3(4, 64, 2), 256, 0, stream>>>(
        ffn1b, w2b, ffn2f, nullptr, nullptr, 1.0f, 8192, 512, 1024, 2048,
        1024, 1024, 8192L * 512);

    // ln2: residual = out1f + ffn2f + ffn2b + b_ffn2
    ln_kernel<false, 2, true><<<8192, 128, 0, stream>>>(
        out1f, ffn2f, ffn2b, b_ffn2, g2, b2, nullptr, finalb);

    // logits = final @ w_vocab^T + b_vocab  -- 128^2 double-buffered pipeline,
    // 2 blocks/CU, 25 bands of 10 bc-tiles, NT stores (R8 proven).
    gemm128v<10><<<16000, 256, 0, stream>>>(finalb, wvocb, out, b_vocab, 32000, 512);
}

// Round 11
// 529.697 us; speedup vs baseline: 1.0588x; 1.0110x over previous
//
#include <hip/hip_runtime.h>
#include <hip/hip_bf16.h>

typedef __bf16 bf16;
typedef __attribute__((ext_vector_type(4))) __bf16 bf16x4;
typedef __attribute__((ext_vector_type(8))) __bf16 bf16x8;
typedef __attribute__((ext_vector_type(4))) float f32x4;

__device__ inline void gload_lds16(const bf16* g, bf16* l) {
    __builtin_amdgcn_global_load_lds(
        (const __attribute__((address_space(1))) void*)g,
        (__attribute__((address_space(3))) void*)l, 16, 0, 0);
}

// ---------------------------------------------------------------- embed + weight cvt (merged)
struct CvtArgs {
    const float* src[6];
    bf16* dst[6];
    long n4[6];
    float scale[6];
};
// blocks 0..4095: embedding (2 rows each); blocks 4096..5631: 6x256 cvt blocks.
__global__ void embed_cvt(CvtArgs a, const int* __restrict__ x,
                          const float* __restrict__ we, const float* __restrict__ pe,
                          float* __restrict__ emb_f, bf16* __restrict__ emb_b) {
    int b = blockIdx.x;
    int tid = threadIdx.x;           // 256
    if (b < 4096) {
        int row = b * 2 + (tid >> 7);
        int c = tid & 127;
        int tok = x[row];
        int s = row & 2047;
        float4 w = ((const float4*)we)[(long)tok * 128 + c];
        float4 p = ((const float4*)pe)[(long)s * 128 + c];
        float4 e = { w.x + p.x, w.y + p.y, w.z + p.z, w.w + p.w };
        ((float4*)emb_f)[(long)row * 128 + c] = e;
        bf16x4 eb = { (bf16)e.x, (bf16)e.y, (bf16)e.z, (bf16)e.w };
        ((bf16x4*)emb_b)[(long)row * 128 + c] = eb;
    } else {
        int bb = b - 4096;           // 0..1535
        int j  = bb >> 8;            // tensor 0..5
        int bx = bb & 255;
        const float* __restrict__ src = a.src[j];
        bf16* __restrict__ dst = a.dst[j];
        long n4 = a.n4[j];
        float sc = a.scale[j];
        long i = (long)bx * 256 + tid;
        long stride = 256 * 256;
        for (; i < n4; i += stride) {
            float4 v = ((const float4*)src)[i];
            bf16x4 o = { (bf16)(v.x * sc), (bf16)(v.y * sc), (bf16)(v.z * sc), (bf16)(v.w * sc) };
            ((bf16x4*)dst)[i] = o;
        }
    }
}

// ---------------------------------------------------------------- layernorm
// Residual = a + b [+ partials] [+ rb(col bias)].
// C3: 0 = none; 1 = PV split-K x4: add c[k] (k=1..3, buffers stride 8192*512)
// for rows with (row&2047) >= k*512; 2 = always add c (ffn2 split-K x2).
template<bool WF32, int C3, bool RBIAS>
__global__ void ln_kernel(const float* __restrict__ a, const float* __restrict__ b,
                          const float* __restrict__ c, const float* __restrict__ rb,
                          const float* __restrict__ g, const float* __restrict__ bb,
                          float* __restrict__ of, bf16* __restrict__ ob) {
    int row = blockIdx.x;            // 8192
    int t   = threadIdx.x;           // 128
    float4 xa = ((const float4*)a)[(long)row * 128 + t];
    float4 xb = ((const float4*)b)[(long)row * 128 + t];
    float4 xv = { xa.x + xb.x, xa.y + xb.y, xa.z + xb.z, xa.w + xb.w };
    if (C3 == 1) {
        int r = row & 2047;
        #pragma unroll
        for (int k = 1; k <= 3; k++) {
            if (r >= k * 512) {
                float4 xc = ((const float4*)(c + (long)(k - 1) * 8192 * 512))[(long)row * 128 + t];
                xv.x += xc.x; xv.y += xc.y; xv.z += xc.z; xv.w += xc.w;
            }
        }
    } else if (C3 == 2) {
        float4 xc = ((const float4*)c)[(long)row * 128 + t];
        xv.x += xc.x; xv.y += xc.y; xv.z += xc.z; xv.w += xc.w;
    }
    if (RBIAS) {
        float4 rv = ((const float4*)rb)[t];
        xv.x += rv.x; xv.y += rv.y; xv.z += rv.z; xv.w += rv.w;
    }
    float s  = xv.x + xv.y + xv.z + xv.w;
    float sq = xv.x * xv.x + xv.y * xv.y + xv.z * xv.z + xv.w * xv.w;
    #pragma unroll
    for (int o = 32; o > 0; o >>= 1) {
        s  += __shfl_xor(s, o);
        sq += __shfl_xor(sq, o);
    }
    __shared__ float rs[2], rq[2];
    int wid = t >> 6;
    if ((t & 63) == 0) { rs[wid] = s; rq[wid] = sq; }
    __syncthreads();
    s = rs[0] + rs[1]; sq = rq[0] + rq[1];
    float mu   = s * (1.0f / 512.0f);
    float var  = sq * (1.0f / 512.0f) - mu * mu;
    float rstd = rsqrtf(var + 1e-5f);
    float4 gv = ((const float4*)g)[t];
    float4 bv = ((const float4*)bb)[t];
    float4 y = { (xv.x - mu) * rstd * gv.x + bv.x,
                 (xv.y - mu) * rstd * gv.y + bv.y,
                 (xv.z - mu) * rstd * gv.z + bv.z,
                 (xv.w - mu) * rstd * gv.w + bv.w };
    if (WF32) ((float4*)of)[(long)row * 128 + t] = y;
    bf16x4 yb = { (bf16)y.x, (bf16)y.y, (bf16)y.z, (bf16)y.w };
    ((bf16x4*)ob)[(long)row * 128 + t] = yb;
}

// ---------------------------------------------------------------- causal softmax
__global__ void softmax_causal(const float* __restrict__ sc, bf16* __restrict__ pr) {
    int row = blockIdx.x;            // 8192
    int z = row >> 11, q = row & 2047;
    const float* srow = sc + ((long)z * 2048 + q) * 2048;
    bf16*        prow = pr + ((long)z * 2048 + q) * 2048;
    int t = threadIdx.x;             // 256, each handles 8 cols
    float v[8];
    int c0 = t * 8;
    if (t <= (q >> 3)) {
        float4 v0 = ((const float4*)srow)[t * 2];
        float4 v1 = ((const float4*)srow)[t * 2 + 1];
        v[0] = v0.x; v[1] = v0.y; v[2] = v0.z; v[3] = v0.w;
        v[4] = v1.x; v[5] = v1.y; v[6] = v1.z; v[7] = v1.w;
    } else {
        #pragma unroll
        for (int j = 0; j < 8; j++) v[j] = -1e30f;
    }
    float mx = -1e30f;
    #pragma unroll
    for (int j = 0; j < 8; j++) {
        if (c0 + j > q) v[j] = -1e30f;
        mx = fmaxf(mx, v[j]);
    }
    int lane = t & 63, wid = t >> 6;
    #pragma unroll
    for (int o = 32; o > 0; o >>= 1) mx = fmaxf(mx, __shfl_xor(mx, o));
    __shared__ float redm[4], reds[4];
    if (lane == 0) redm[wid] = mx;
    __syncthreads();
    mx = fmaxf(fmaxf(redm[0], redm[1]), fmaxf(redm[2], redm[3]));
    float p[8]; float sum = 0.f;
    #pragma unroll
    for (int j = 0; j < 8; j++) {
        p[j] = (c0 + j <= q) ? __expf(v[j] - mx) : 0.f;
        sum += p[j];
    }
    #pragma unroll
    for (int o = 32; o > 0; o >>= 1) sum += __shfl_xor(sum, o);
    if (lane == 0) reds[wid] = sum;
    __syncthreads();
    sum = reds[0] + reds[1] + reds[2] + reds[3];
    float inv = 1.0f / sum;
    int wlim = ((q >> 7) + 1) * 128;             // causal 128-block boundary
    if (c0 < wlim) {
        bf16x8 o;
        #pragma unroll
        for (int j = 0; j < 8; j++) o[j] = (bf16)(p[j] * inv);
        *(bf16x8*)&prow[c0] = o;
    }
}

// ---------------------------------------------------------------- epilogue tags
enum { EPI_F32 = 0, EPI_BF16 = 1, EPI_VT = 2, EPI_BIAS_RELU_BF16 = 3, EPI_BIAS_F32 = 4,
       EPI_QKV = 5, EPI_BIAS_F32_NT = 6 };
enum { ZB_BATCH = 0, ZB_PV = 1 };

// ---------------------------------------------------------------- 128^2 GEMM (proven)
// ZB_BATCH: z = batch (or K-chunk); A/B/Cf shifted by z*sA/sB/sC elements.
// ZB_PV   : z = batch*4 + chunk. Causal P@V with split-K chunks of 512:
//           chunk c covers k in [c*512, min(keff, c*512+512)).
//           Cf base for chunk c is Cf + c*8192*512 (pv0..pv3 contiguous);
//           blocks whose causal keff <= lo exit early (block-uniform).
template<int EPI, bool CAUSAL_SKIP, bool CAUSAL_K, bool XCD, int ZMODE>
__global__ __launch_bounds__(256)
void gemm_bt(const bf16* __restrict__ A, const bf16* __restrict__ B,
             float* __restrict__ Cf, bf16* __restrict__ Cb,
             const float* __restrict__ bias, float scale,
             int M, int N, int K, int Krow, long sA, long sB, long sC) {
    int br, bc;
    if (XCD) {
        int nwg = gridDim.x * gridDim.y;         // caller ensures %8==0
        int lin = blockIdx.y * gridDim.x + blockIdx.x;
        lin = (lin & 7) * (nwg >> 3) + (lin >> 3);
        br = lin / gridDim.x; bc = lin - br * gridDim.x;
    } else { br = blockIdx.y; bc = blockIdx.x; }
    int z = blockIdx.z;
    int Kext = K;
    if (ZMODE == ZB_BATCH) {
        A += (long)z * sA; B += (long)z * sB; Cf += (long)z * sC;
    } else if (ZMODE == ZB_PV) {
        int batch = z >> 2, chunk = z & 3;
        A += (long)batch * sA; B += (long)batch * sB;
        Cf += (long)chunk * (8192L * 512) + (long)batch * sC;
        int keff = min(K, (br + 1) * 128);
        int lo = chunk * 512;
        if (keff <= lo) return;                  // block-uniform early exit
        A += lo; B += lo;
        Kext = min(keff, lo + 512) - lo;
    }
    if (CAUSAL_SKIP && bc > br) return;
    if (CAUSAL_K) Kext = min(Kext, (br + 1) * 128);
    __shared__ bf16 As[128 * 64];
    __shared__ bf16 Bs[128 * 64];
    int tid = threadIdx.x;
    int lane = tid & 63, wid = tid >> 6;
    int wm = (wid >> 1) * 64, wn = (wid & 1) * 64;
    f32x4 acc[4][4] = {};
    int rowA0 = br * 128, colB0 = bc * 128;
    int rsub = lane >> 3;
    int csub = ((lane & 7) ^ rsub) * 8;            // pre-swizzled source col
    int rdsw = (lane & 7) * 8;                     // read-side XOR
    for (int kt = 0; kt < Kext; kt += 64) {
        const bf16* Ag = A + (long)rowA0 * Krow + kt;
        const bf16* Bg = B + (long)colB0 * Krow + kt;
        #pragma unroll
        for (int i = 0; i < 4; i++) {
            int seg = wid * 4 + i;
            int r = seg * 8 + rsub;
            gload_lds16(&Ag[(long)r * Krow + csub], &As[seg * 512]);
            gload_lds16(&Bg[(long)r * Krow + csub], &Bs[seg * 512]);
        }
        __syncthreads();
        #pragma unroll
        for (int kk = 0; kk < 2; kk++) {
            bf16x8 af[4], bfr[4];
            int ko = (kk * 32 + (lane >> 4) * 8) ^ rdsw;
            #pragma unroll
            for (int m = 0; m < 4; m++) af[m]  = *(const bf16x8*)&As[(wm + m * 16 + (lane & 15)) * 64 + ko];
            #pragma unroll
            for (int n = 0; n < 4; n++) bfr[n] = *(const bf16x8*)&Bs[(wn + n * 16 + (lane & 15)) * 64 + ko];
            #pragma unroll
            for (int m = 0; m < 4; m++)
                #pragma unroll
                for (int n = 0; n < 4; n++)
                    acc[m][n] = __builtin_amdgcn_mfma_f32_16x16x32_bf16(af[m], bfr[n], acc[m][n], 0, 0, 0);
        }
        __syncthreads();
    }
    #pragma unroll
    for (int m = 0; m < 4; m++) {
        #pragma unroll
        for (int n = 0; n < 4; n++) {
            #pragma unroll
            for (int j = 0; j < 4; j++) {
                int row = rowA0 + wm + m * 16 + (lane >> 4) * 4 + j;
                int col = colB0 + wn + n * 16 + (lane & 15);
                float v = acc[m][n][j];
                if (EPI == EPI_F32) {
                    Cf[(long)row * N + col] = v;        // z-offsets already applied
                } else if (EPI == EPI_BF16) {
                    Cb[(long)row * N + col] = (bf16)(v * scale);
                } else if (EPI == EPI_VT) {
                    int b = row >> 11, k = row & 2047;
                    Cb[((long)b * 512 + col) * 2048 + k] = (bf16)v;
                } else if (EPI == EPI_BIAS_RELU_BF16) {
                    float y = fmaxf(v + bias[col], 0.0f);
                    Cb[(long)row * N + col] = (bf16)y;
                } else if (EPI == EPI_BIAS_F32) {
                    Cf[(long)row * N + col] = v + bias[col];
                }
            }
        }
    }
}

// ---------------------------------------------------------------- 256^2 deep-pipeline GEMM (BK=64)
template<int EPI, bool XCD, bool CSKIP, int BANDW, int NT>
__global__ __launch_bounds__(512)
void gemm256(const bf16* __restrict__ A, const bf16* __restrict__ B,
             float* __restrict__ Cf, bf16* __restrict__ Cb,
             const float* __restrict__ bias, int N, int K,
             long sA, long sB, long sC) {
    int br, bc;
    if (XCD) {
        int nwg = gridDim.x * gridDim.y;          // caller ensures %8==0
        int lin = blockIdx.y * gridDim.x + blockIdx.x;
        lin = (lin & 7) * (nwg >> 3) + (lin >> 3);
        if (BANDW > 0) {
            int per = BANDW * gridDim.y;          // blocks per band
            int band = lin / per, w2 = lin - band * per;
            br = w2 / BANDW; bc = band * BANDW + (w2 - br * BANDW);
        } else {
            br = lin / gridDim.x; bc = lin - br * gridDim.x;
        }
    } else { br = blockIdx.y; bc = blockIdx.x; }
    if (CSKIP && bc > br) return;                 // causal skip at 256-tile granularity
    int z = blockIdx.z;
    A  += (long)z * sA;
    B  += (long)z * sB;
    Cf += (long)z * sC;
    __shared__ bf16 lds[2][2][256 * 64];          // [buf][A/B] = 128 KiB
    int tid = threadIdx.x;
    int lane = tid & 63, wid = tid >> 6;
    int wm2 = wid >> 2, wn4 = wid & 3;
    long rowA0 = (long)br * 256, colB0 = (long)bc * 256;
    int rsub = lane >> 3;
    int csw  = ((lane & 7) ^ rsub) * 8;           // pre-swizzled source col
    int l15 = lane & 15;
    int rdxor = (lane & 7) << 3;
    int kbase = (lane >> 4) * 8;
    const bf16* Abase = A + rowA0 * K;
    const bf16* Bbase = B + colB0 * K;
    f32x4 acc[8][4] = {};

    auto stage = [&](int t) {
        int buf = t & 1;
        const bf16* Ag = Abase + t * 64;
        const bf16* Bg = Bbase + t * 64;
        #pragma unroll
        for (int i = 0; i < 4; i++) {
            int seg = wid * 4 + i;                // 0..31
            long r = seg * 8 + rsub;
            gload_lds16(&Ag[r * K + csw], &lds[buf][0][seg * 512]);
        }
        #pragma unroll
        for (int i = 0; i < 4; i++) {
            int seg = wid * 4 + i;
            long r = seg * 8 + rsub;
            gload_lds16(&Bg[r * K + csw], &lds[buf][1][seg * 512]);
        }
    };

    stage(0);
    stage(1);

    for (int t = 0; t < NT; t++) {
        int buf = t & 1;
        if (t == NT - 1) asm volatile("s_waitcnt vmcnt(0)" ::: "memory");
        else             asm volatile("s_waitcnt vmcnt(8)" ::: "memory");
        __builtin_amdgcn_s_barrier();             // everyone's tile-t data visible
        const bf16* As = lds[buf][0];
        const bf16* Bs = lds[buf][1];
        bf16x8 bfr[2][4], af[2][4];
        #pragma unroll
        for (int kk = 0; kk < 2; kk++)
            #pragma unroll
            for (int n = 0; n < 4; n++) {
                int r = wn4 * 64 + n * 16 + l15;
                bfr[kk][n] = *(const bf16x8*)&Bs[r * 64 + ((kk * 32 + kbase) ^ rdxor)];
            }
        #pragma unroll
        for (int kk = 0; kk < 2; kk++)
            #pragma unroll
            for (int m = 0; m < 4; m++) {
                int r = wm2 * 128 + m * 16 + l15;
                af[kk][m] = *(const bf16x8*)&As[r * 64 + ((kk * 32 + kbase) ^ rdxor)];
            }
        __builtin_amdgcn_s_setprio(1);
        #pragma unroll
        for (int kk = 0; kk < 2; kk++)
            #pragma unroll
            for (int m = 0; m < 4; m++)
                #pragma unroll
                for (int n = 0; n < 4; n++)
                    acc[m][n] = __builtin_amdgcn_mfma_f32_16x16x32_bf16(af[kk][m], bfr[kk][n], acc[m][n], 0, 0, 0);
        __builtin_amdgcn_s_setprio(0);
        // second half of A rows
        #pragma unroll
        for (int kk = 0; kk < 2; kk++)
            #pragma unroll
            for (int m = 0; m < 4; m++) {
                int r = wm2 * 128 + 64 + m * 16 + l15;
                af[kk][m] = *(const bf16x8*)&As[r * 64 + ((kk * 32 + kbase) ^ rdxor)];
            }
        asm volatile("s_waitcnt lgkmcnt(0)" ::: "memory"); // all my buf reads done
        __builtin_amdgcn_sched_barrier(0);
        __builtin_amdgcn_s_barrier();             // ALL waves done reading buf
        if (t + 2 < NT) stage(t + 2);             // overwrite buf; flies across iters
        __builtin_amdgcn_s_setprio(1);
        #pragma unroll
        for (int kk = 0; kk < 2; kk++)
            #pragma unroll
            for (int m = 0; m < 4; m++)
                #pragma unroll
                for (int n = 0; n < 4; n++)
                    acc[4 + m][n] = __builtin_amdgcn_mfma_f32_16x16x32_bf16(af[kk][m], bfr[kk][n], acc[4 + m][n], 0, 0, 0);
        __builtin_amdgcn_s_setprio(0);
    }

    if constexpr (EPI == EPI_QKV) {
        // N=1536; 256-col panels are block-uniform: 0-1=Q, 2-3=K, 4-5=V.
        int region = (int)(colB0 >> 9);           // 0=Q, 1=K, 2=V
        if (region < 2) {
            bf16* dst = Cb + (long)region * (8192L * 512);
            int cb = ((int)colB0 & 511) + wn4 * 64;
            #pragma unroll
            for (int m = 0; m < 8; m++)
                #pragma unroll
                for (int n = 0; n < 4; n++)
                    #pragma unroll
                    for (int j = 0; j < 4; j++) {
                        long row = rowA0 + wm2 * 128 + m * 16 + (lane >> 4) * 4 + j;
                        int c = cb + n * 16 + l15;
                        dst[row * 512 + c] = (bf16)acc[m][n][j];
                    }
        } else {
            bf16* vtb = Cb + 2L * 8192 * 512;
            int cb = ((int)colB0 - 1024) + wn4 * 64;
            #pragma unroll
            for (int m = 0; m < 8; m++)
                #pragma unroll
                for (int n = 0; n < 4; n++) {
                    long k0 = rowA0 + wm2 * 128 + m * 16 + (lane >> 4) * 4;
                    long b = k0 >> 11, k = k0 & 2047;
                    int c = cb + n * 16 + l15;
                    bf16x4 pk = { (bf16)acc[m][n][0], (bf16)acc[m][n][1],
                                  (bf16)acc[m][n][2], (bf16)acc[m][n][3] };
                    *(bf16x4*)&vtb[(b * 512 + c) * 2048 + k] = pk;
                }
        }
    } else {
        #pragma unroll
        for (int m = 0; m < 8; m++) {
            #pragma unroll
            for (int n = 0; n < 4; n++) {
                #pragma unroll
                for (int j = 0; j < 4; j++) {
                    long row = rowA0 + wm2 * 128 + m * 16 + (lane >> 4) * 4 + j;
                    long col = colB0 + wn4 * 64 + n * 16 + l15;
                    float v = acc[m][n][j];
                    if (EPI == EPI_BIAS_F32) {
                        Cf[row * N + col] = v + bias[col];
                    } else if (EPI == EPI_BIAS_F32_NT) {
                        __builtin_nontemporal_store(v + bias[col], &Cf[row * N + col]);
                    } else if (EPI == EPI_BIAS_RELU_BF16) {
                        Cb[row * N + col] = (bf16)fmaxf(v + bias[col], 0.0f);
                    } else if (EPI == EPI_F32) {
                        Cf[row * N + col] = v;
                    }
                }
            }
        }
    }
}

// ---------------------------------------------------------------- vocab GEMM (R8 proven)
template<int BANDB>
__global__ __launch_bounds__(256)
void gemm128v(const bf16* __restrict__ A, const bf16* __restrict__ B,
              float* __restrict__ C, const float* __restrict__ bias,
              int N, int K) {
    const int NBR = 64;                            // 8192/128 row-tiles
    const int NT  = 8;                             // K=512 / 64
    int nwg = gridDim.x;                           // 16000 (%8==0)
    int lin = blockIdx.x;
    lin = (lin & 7) * (nwg >> 3) + (lin >> 3);     // XCD-contiguous chunks
    int per = BANDB * NBR;
    int band = lin / per, w2 = lin - band * per;
    int br = w2 / BANDB, bc = band * BANDB + (w2 - br * BANDB);

    __shared__ bf16 lds[2][2][128 * 64];           // 64 KiB -> 2 blocks/CU
    int tid = threadIdx.x;
    int lane = tid & 63, wid = tid >> 6;
    int wm = (wid >> 1) * 64, wn = (wid & 1) * 64;
    int rsub = lane >> 3;
    int csub = ((lane & 7) ^ rsub) * 8;            // pre-swizzled source col
    int rdsw = (lane & 7) * 8;                     // read-side XOR
    long rowA0 = (long)br * 128, colB0 = (long)bc * 128;
    const bf16* Abase = A + rowA0 * K;
    const bf16* Bbase = B + colB0 * K;
    f32x4 acc[4][4] = {};

    auto stage = [&](int t) {                      // 8 VMEM issues/thread
        int buf = t & 1;
        const bf16* Ag = Abase + t * 64;
        const bf16* Bg = Bbase + t * 64;
        #pragma unroll
        for (int i = 0; i < 4; i++) {
            int seg = wid * 4 + i;                 // 0..15
            long r = seg * 8 + rsub;
            gload_lds16(&Ag[r * K + csub], &lds[buf][0][seg * 512]);
        }
        #pragma unroll
        for (int i = 0; i < 4; i++) {
            int seg = wid * 4 + i;
            long r = seg * 8 + rsub;
            gload_lds16(&Bg[r * K + csub], &lds[buf][1][seg * 512]);
        }
    };

    stage(0);
    stage(1);

    for (int t = 0; t < NT; t++) {
        int buf = t & 1;
        if (t == NT - 1) asm volatile("s_waitcnt vmcnt(0)" ::: "memory");
        else             asm volatile("s_waitcnt vmcnt(8)" ::: "memory");
        __builtin_amdgcn_s_barrier();              // tile-t data visible
        const bf16* As = lds[buf][0];
        const bf16* Bs = lds[buf][1];
        __builtin_amdgcn_s_setprio(1);
        #pragma unroll
        for (int kk = 0; kk < 2; kk++) {
            bf16x8 af[4], bfr[4];
            int ko = (kk * 32 + (lane >> 4) * 8) ^ rdsw;
            #pragma unroll
            for (int m = 0; m < 4; m++) af[m]  = *(const bf16x8*)&As[(wm + m * 16 + (lane & 15)) * 64 + ko];
            #pragma unroll
            for (int n = 0; n < 4; n++) bfr[n] = *(const bf16x8*)&Bs[(wn + n * 16 + (lane & 15)) * 64 + ko];
            #pragma unroll
            for (int m = 0; m < 4; m++)
                #pragma unroll
                for (int n = 0; n < 4; n++)
                    acc[m][n] = __builtin_amdgcn_mfma_f32_16x16x32_bf16(af[m], bfr[n], acc[m][n], 0, 0, 0);
        }
        __builtin_amdgcn_s_setprio(0);
        asm volatile("s_waitcnt lgkmcnt(0)" ::: "memory"); // my buf reads done
        __builtin_amdgcn_sched_barrier(0);
        __builtin_amdgcn_s_barrier();              // ALL waves done reading buf
        if (t + 2 < NT) stage(t + 2);              // overwrite buf
    }

    #pragma unroll
    for (int m = 0; m < 4; m++) {
        #pragma unroll
        for (int n = 0; n < 4; n++) {
            int col = (int)colB0 + wn + n * 16 + (lane & 15);
            float bcol = bias[col];
            #pragma unroll
            for (int j = 0; j < 4; j++) {
                long row = rowA0 + wm + m * 16 + (lane >> 4) * 4 + j;
                __builtin_nontemporal_store(acc[m][n][j] + bcol, &C[row * N + col]);
            }
        }
    }
}

// ---------------------------------------------------------------- launch
extern "C" void kernel_launch(void* const* d_in, const int* in_sizes, int n_in,
                              void* d_out, int out_size, void* d_ws, size_t ws_size,
                              hipStream_t stream) {
    const int*   x       = (const int*)d_in[0];
    const float* word_emb = (const float*)d_in[1];
    const float* pos_emb  = (const float*)d_in[2];
    const float* Wq = (const float*)d_in[3];
    const float* Wk = (const float*)d_in[4];
    const float* Wv = (const float*)d_in[5];
    const float* g1 = (const float*)d_in[6];
    const float* b1 = (const float*)d_in[7];
    const float* w_ffn1 = (const float*)d_in[8];
    const float* b_ffn1 = (const float*)d_in[9];
    const float* w_ffn2 = (const float*)d_in[10];
    const float* b_ffn2 = (const float*)d_in[11];
    const float* g2 = (const float*)d_in[12];
    const float* b2 = (const float*)d_in[13];
    const float* w_vocab = (const float*)d_in[14];
    const float* b_vocab = (const float*)d_in[15];
    float* out = (float*)d_out;

    char* w = (char*)d_ws;
    auto alloc = [&](size_t bytes) { char* p = w; w += (bytes + 255) & ~255ULL; return p; };
    // NOTE: wqb/wkb/wvb must stay contiguous ([1536 x 512] fused weight);
    //       qb/kb/vt contiguous (EPI_QKV writes all three off qb);
    //       ctx/pv1/pv2/pv3 contiguous (ZB_PV chunk offset = 8192*512 floats);
    //       ffn2f/ffn2b contiguous (split-K sC = 8192*512 floats).
    bf16* wqb   = (bf16*)alloc(512 * 512 * 2);
    bf16* wkb   = (bf16*)alloc(512 * 512 * 2);
    bf16* wvb   = (bf16*)alloc(512 * 512 * 2);
    bf16* w1b   = (bf16*)alloc(2048 * 512 * 2);
    bf16* w2b   = (bf16*)alloc(512 * 2048 * 2);
    bf16* wvocb = (bf16*)alloc((size_t)32000 * 512 * 2);
    float* embf = (float*)alloc((size_t)8192 * 512 * 4);
    bf16* embb  = (bf16*)alloc((size_t)8192 * 512 * 2);   // also final_b (aliased)
    bf16* qb    = (bf16*)alloc((size_t)8192 * 512 * 2);
    bf16* kb    = (bf16*)alloc((size_t)8192 * 512 * 2);   // also out1_b (aliased)
    bf16* vt    = (bf16*)alloc((size_t)8192 * 512 * 2);
    float* scores = (float*)alloc((size_t)4 * 2048 * 2048 * 4); // also ffn1_b (aliased)
    bf16* probs = (bf16*)alloc((size_t)4 * 2048 * 2048 * 2);
    float* ctx  = (float*)alloc((size_t)8192 * 512 * 4);  // pv0
    float* pv1  = (float*)alloc((size_t)8192 * 512 * 4);  // pv chunk-1 partial
    float* pv2  = (float*)alloc((size_t)8192 * 512 * 4);  // pv chunk-2 partial
    float* pv3  = (float*)alloc((size_t)8192 * 512 * 4);  // pv chunk-3 partial
    float* out1f = (float*)alloc((size_t)8192 * 512 * 4);
    float* ffn2f = (float*)alloc((size_t)8192 * 512 * 4); // ffn2 chunk-0 partial
    float* ffn2b = (float*)alloc((size_t)8192 * 512 * 4); // ffn2 chunk-1 partial
    bf16* ffn1b = (bf16*)scores;   // alias: scores dead after softmax
    bf16* out1b = kb;              // alias: kb dead after scores GEMM
    bf16* finalb = embb;           // alias: embb dead after QKV GEMM
    (void)pv2; (void)pv3;

    const float qscale = 0.044194173824159216f; // 1/sqrt(512)

    // merged: embedding (blocks 0..4095) + all six weight cvts (blocks 4096..5631)
    CvtArgs ca;
    ca.src[0] = Wq;      ca.dst[0] = wqb;   ca.n4[0] = 512 * 512 / 4;          ca.scale[0] = qscale;
    ca.src[1] = Wk;      ca.dst[1] = wkb;   ca.n4[1] = 512 * 512 / 4;          ca.scale[1] = 1.0f;
    ca.src[2] = Wv;      ca.dst[2] = wvb;   ca.n4[2] = 512 * 512 / 4;          ca.scale[2] = 1.0f;
    ca.src[3] = w_ffn1;  ca.dst[3] = w1b;   ca.n4[3] = 2048 * 512 / 4;         ca.scale[3] = 1.0f;
    ca.src[4] = w_ffn2;  ca.dst[4] = w2b;   ca.n4[4] = 512 * 2048 / 4;         ca.scale[4] = 1.0f;
    ca.src[5] = w_vocab; ca.dst[5] = wvocb; ca.n4[5] = (long)32000 * 512 / 4;  ca.scale[5] = 1.0f;
    embed_cvt<<<5632, 256, 0, stream>>>(ca, x, word_emb, pos_emb, embf, embb);

    // fused Q|K|V projection: emb[8192x512] @ Wqkv^T[1536x512] -> qb,kb,vt
    gemm256<EPI_QKV, true, false, 0, 8><<<dim3(6, 32, 1), 512, 0, stream>>>(
        embb, wqb, nullptr, qb, nullptr, 1536, 512, 0, 0, 0);

    // scores = Q @ K^T: 128^2 tiles, 544 active blocks (~2.1/CU), causal skip
    // (R0-proven config; 256^2 ran at 0.56 blocks/CU = single-block latency).
    gemm_bt<EPI_F32, true, false, false, ZB_BATCH><<<dim3(16, 16, 4), 256, 0, stream>>>(
        qb, kb, scores, nullptr, nullptr, 1.0f, 2048, 2048, 512, 512,
        (long)2048 * 512, (long)2048 * 512, (long)2048 * 2048);

    softmax_causal<<<8192, 256, 0, stream>>>(scores, probs);

    // context = P @ V, split-K x4 without atomics: chunk c covers k in
    // [c*512, min(keff, c*512+512)) -> pv0..pv3; summed inside ln1.
    // 640 active blocks (2.5/CU), straggler tail 8 K-steps.
    gemm_bt<EPI_F32, false, false, false, ZB_PV><<<dim3(4, 16, 16), 256, 0, stream>>>(
        probs, vt, ctx, nullptr, nullptr, 1.0f, 2048, 512, 2048, 2048,
        (long)2048 * 2048, (long)512 * 2048, (long)2048 * 512);

    // ln1: residual = embf + pv0 (+ pv1/pv2/pv3 row-conditionally)
    ln_kernel<true, 1, false><<<8192, 128, 0, stream>>>(
        embf, ctx, pv1, nullptr, g1, b1, out1f, out1b);

    // ffn1 = relu(out1 @ W1^T + b1)  -- 256^2 deep pipeline
    gemm256<EPI_BIAS_RELU_BF16, true, false, 0, 8><<<dim3(8, 32, 1), 512, 0, stream>>>(
        out1b, w1b, nullptr, ffn1b, b_ffn1, 2048, 512, 0, 0, 0);

    // ffn2 = ffn1 @ W2^T, split-K x2 without atomics: chunk z covers K cols
    // [z*1024, z*1024+1024) -> ffn2f/ffn2b; summed (+b_ffn2) inside ln2.
    gemm_bt<EPI_F32, false, false, false, ZB_BATCH><<<dim3(4, 64, 2), 256, 0, stream>>>(
        ffn1b, w2b, ffn2f, nullptr, nullptr, 1.0f, 8192, 512, 1024, 2048,
        1024, 1024, 8192L * 512);

    // ln2: residual = out1f + ffn2f + ffn2b + b_ffn2
    ln_kernel<false, 2, true><<<8192, 128, 0, stream>>>(
        out1f, ffn2f, ffn2b, b_ffn2, g2, b2, nullptr, finalb);

    // logits = final @ w_vocab^T + b_vocab  -- 128^2 double-buffered pipeline,
    // 2 blocks/CU, 25 bands of 10 bc-tiles, NT stores (R8 proven).
    gemm128v<10><<<16000, 256, 0, stream>>>(finalb, wvocb, out, b_vocab, 32000, 512);
}

// Round 12
// 528.446 us; speedup vs baseline: 1.0613x; 1.0024x over previous
//
#include <hip/hip_runtime.h>
#include <hip/hip_bf16.h>

typedef __bf16 bf16;
typedef __attribute__((ext_vector_type(4))) __bf16 bf16x4;
typedef __attribute__((ext_vector_type(8))) __bf16 bf16x8;
typedef __attribute__((ext_vector_type(4))) float f32x4;

__device__ inline void gload_lds16(const bf16* g, bf16* l) {
    __builtin_amdgcn_global_load_lds(
        (const __attribute__((address_space(1))) void*)g,
        (__attribute__((address_space(3))) void*)l, 16, 0, 0);
}

// ---------------------------------------------------------------- embed + weight cvt (merged)
struct CvtArgs {
    const float* src[6];
    bf16* dst[6];
    long n4[6];
    float scale[6];
};
// blocks 0..4095: embedding (2 rows each); blocks 4096..5631: 6x256 cvt blocks.
__global__ void embed_cvt(CvtArgs a, const int* __restrict__ x,
                          const float* __restrict__ we, const float* __restrict__ pe,
                          float* __restrict__ emb_f, bf16* __restrict__ emb_b) {
    int b = blockIdx.x;
    int tid = threadIdx.x;           // 256
    if (b < 4096) {
        int row = b * 2 + (tid >> 7);
        int c = tid & 127;
        int tok = x[row];
        int s = row & 2047;
        float4 w = ((const float4*)we)[(long)tok * 128 + c];
        float4 p = ((const float4*)pe)[(long)s * 128 + c];
        float4 e = { w.x + p.x, w.y + p.y, w.z + p.z, w.w + p.w };
        ((float4*)emb_f)[(long)row * 128 + c] = e;
        bf16x4 eb = { (bf16)e.x, (bf16)e.y, (bf16)e.z, (bf16)e.w };
        ((bf16x4*)emb_b)[(long)row * 128 + c] = eb;
    } else {
        int bb = b - 4096;           // 0..1535
        int j  = bb >> 8;            // tensor 0..5
        int bx = bb & 255;
        const float* __restrict__ src = a.src[j];
        bf16* __restrict__ dst = a.dst[j];
        long n4 = a.n4[j];
        float sc = a.scale[j];
        long i = (long)bx * 256 + tid;
        long stride = 256 * 256;
        for (; i < n4; i += stride) {
            float4 v = ((const float4*)src)[i];
            bf16x4 o = { (bf16)(v.x * sc), (bf16)(v.y * sc), (bf16)(v.z * sc), (bf16)(v.w * sc) };
            ((bf16x4*)dst)[i] = o;
        }
    }
}

// ---------------------------------------------------------------- layernorm
// Residual = a + b [+ partials] [+ rb(col bias)].
// C3: 0 = none; 1 = PV split-K x4: add c[k] (k=1..3, buffers stride 8192*512)
// for rows with (row&2047) >= k*512; 2 = always add c (ffn2 split-K x2).
template<bool WF32, int C3, bool RBIAS>
__global__ void ln_kernel(const float* __restrict__ a, const float* __restrict__ b,
                          const float* __restrict__ c, const float* __restrict__ rb,
                          const float* __restrict__ g, const float* __restrict__ bb,
                          float* __restrict__ of, bf16* __restrict__ ob) {
    int row = blockIdx.x;            // 8192
    int t   = threadIdx.x;           // 128
    float4 xa = ((const float4*)a)[(long)row * 128 + t];
    float4 xb = ((const float4*)b)[(long)row * 128 + t];
    float4 xv = { xa.x + xb.x, xa.y + xb.y, xa.z + xb.z, xa.w + xb.w };
    if (C3 == 1) {
        int r = row & 2047;
        #pragma unroll
        for (int k = 1; k <= 3; k++) {
            if (r >= k * 512) {
                float4 xc = ((const float4*)(c + (long)(k - 1) * 8192 * 512))[(long)row * 128 + t];
                xv.x += xc.x; xv.y += xc.y; xv.z += xc.z; xv.w += xc.w;
            }
        }
    } else if (C3 == 2) {
        float4 xc = ((const float4*)c)[(long)row * 128 + t];
        xv.x += xc.x; xv.y += xc.y; xv.z += xc.z; xv.w += xc.w;
    }
    if (RBIAS) {
        float4 rv = ((const float4*)rb)[t];
        xv.x += rv.x; xv.y += rv.y; xv.z += rv.z; xv.w += rv.w;
    }
    float s  = xv.x + xv.y + xv.z + xv.w;
    float sq = xv.x * xv.x + xv.y * xv.y + xv.z * xv.z + xv.w * xv.w;
    #pragma unroll
    for (int o = 32; o > 0; o >>= 1) {
        s  += __shfl_xor(s, o);
        sq += __shfl_xor(sq, o);
    }
    __shared__ float rs[2], rq[2];
    int wid = t >> 6;
    if ((t & 63) == 0) { rs[wid] = s; rq[wid] = sq; }
    __syncthreads();
    s = rs[0] + rs[1]; sq = rq[0] + rq[1];
    float mu   = s * (1.0f / 512.0f);
    float var  = sq * (1.0f / 512.0f) - mu * mu;
    float rstd = rsqrtf(var + 1e-5f);
    float4 gv = ((const float4*)g)[t];
    float4 bv = ((const float4*)bb)[t];
    float4 y = { (xv.x - mu) * rstd * gv.x + bv.x,
                 (xv.y - mu) * rstd * gv.y + bv.y,
                 (xv.z - mu) * rstd * gv.z + bv.z,
                 (xv.w - mu) * rstd * gv.w + bv.w };
    if (WF32) ((float4*)of)[(long)row * 128 + t] = y;
    bf16x4 yb = { (bf16)y.x, (bf16)y.y, (bf16)y.z, (bf16)y.w };
    ((bf16x4*)ob)[(long)row * 128 + t] = yb;
}

// ---------------------------------------------------------------- causal softmax (bf16 scores)
__global__ void softmax_causal(const bf16* __restrict__ sc, bf16* __restrict__ pr) {
    int row = blockIdx.x;            // 8192
    int z = row >> 11, q = row & 2047;
    const bf16* srow = sc + ((long)z * 2048 + q) * 2048;
    bf16*       prow = pr + ((long)z * 2048 + q) * 2048;
    int t = threadIdx.x;             // 256, each handles 8 cols
    float v[8];
    int c0 = t * 8;
    if (t <= (q >> 3)) {
        bf16x8 vb = *(const bf16x8*)&srow[c0];
        #pragma unroll
        for (int j = 0; j < 8; j++) v[j] = (float)vb[j];
    } else {
        #pragma unroll
        for (int j = 0; j < 8; j++) v[j] = -1e30f;
    }
    float mx = -1e30f;
    #pragma unroll
    for (int j = 0; j < 8; j++) {
        if (c0 + j > q) v[j] = -1e30f;
        mx = fmaxf(mx, v[j]);
    }
    int lane = t & 63, wid = t >> 6;
    #pragma unroll
    for (int o = 32; o > 0; o >>= 1) mx = fmaxf(mx, __shfl_xor(mx, o));
    __shared__ float redm[4], reds[4];
    if (lane == 0) redm[wid] = mx;
    __syncthreads();
    mx = fmaxf(fmaxf(redm[0], redm[1]), fmaxf(redm[2], redm[3]));
    float p[8]; float sum = 0.f;
    #pragma unroll
    for (int j = 0; j < 8; j++) {
        p[j] = (c0 + j <= q) ? __expf(v[j] - mx) : 0.f;
        sum += p[j];
    }
    #pragma unroll
    for (int o = 32; o > 0; o >>= 1) sum += __shfl_xor(sum, o);
    if (lane == 0) reds[wid] = sum;
    __syncthreads();
    sum = reds[0] + reds[1] + reds[2] + reds[3];
    float inv = 1.0f / sum;
    int wlim = ((q >> 7) + 1) * 128;             // causal 128-block boundary
    if (c0 < wlim) {
        bf16x8 o;
        #pragma unroll
        for (int j = 0; j < 8; j++) o[j] = (bf16)(p[j] * inv);
        *(bf16x8*)&prow[c0] = o;
    }
}

// ---------------------------------------------------------------- epilogue tags
enum { EPI_F32 = 0, EPI_BF16 = 1, EPI_VT = 2, EPI_BIAS_RELU_BF16 = 3, EPI_BIAS_F32 = 4,
       EPI_QKV = 5, EPI_BIAS_F32_NT = 6 };
enum { ZB_BATCH = 0, ZB_PV = 1 };

// ---------------------------------------------------------------- 128^2 GEMM (proven)
// ZB_BATCH: z = batch (or K-chunk); A/B/Cf/Cb shifted by z*sA/sB/sC elements.
// ZB_PV   : z = batch*4 + chunk. Causal P@V with split-K chunks of 512:
//           chunk c covers k in [c*512, min(keff, c*512+512)).
//           Cf base for chunk c is Cf + c*8192*512 (pv0..pv3 contiguous);
//           blocks whose causal keff <= lo exit early (block-uniform).
template<int EPI, bool CAUSAL_SKIP, bool CAUSAL_K, bool XCD, int ZMODE>
__global__ __launch_bounds__(256)
void gemm_bt(const bf16* __restrict__ A, const bf16* __restrict__ B,
             float* __restrict__ Cf, bf16* __restrict__ Cb,
             const float* __restrict__ bias, float scale,
             int M, int N, int K, int Krow, long sA, long sB, long sC) {
    int br, bc;
    if (XCD) {
        int nwg = gridDim.x * gridDim.y;         // caller ensures %8==0
        int lin = blockIdx.y * gridDim.x + blockIdx.x;
        lin = (lin & 7) * (nwg >> 3) + (lin >> 3);
        br = lin / gridDim.x; bc = lin - br * gridDim.x;
    } else { br = blockIdx.y; bc = blockIdx.x; }
    int z = blockIdx.z;
    int Kext = K;
    if (ZMODE == ZB_BATCH) {
        A += (long)z * sA; B += (long)z * sB; Cf += (long)z * sC; Cb += (long)z * sC;
    } else if (ZMODE == ZB_PV) {
        int batch = z >> 2, chunk = z & 3;
        A += (long)batch * sA; B += (long)batch * sB;
        Cf += (long)chunk * (8192L * 512) + (long)batch * sC;
        int keff = min(K, (br + 1) * 128);
        int lo = chunk * 512;
        if (keff <= lo) return;                  // block-uniform early exit
        A += lo; B += lo;
        Kext = min(keff, lo + 512) - lo;
    }
    if (CAUSAL_SKIP && bc > br) return;
    if (CAUSAL_K) Kext = min(Kext, (br + 1) * 128);
    __shared__ bf16 As[128 * 64];
    __shared__ bf16 Bs[128 * 64];
    int tid = threadIdx.x;
    int lane = tid & 63, wid = tid >> 6;
    int wm = (wid >> 1) * 64, wn = (wid & 1) * 64;
    f32x4 acc[4][4] = {};
    int rowA0 = br * 128, colB0 = bc * 128;
    int rsub = lane >> 3;
    int csub = ((lane & 7) ^ rsub) * 8;            // pre-swizzled source col
    int rdsw = (lane & 7) * 8;                     // read-side XOR
    for (int kt = 0; kt < Kext; kt += 64) {
        const bf16* Ag = A + (long)rowA0 * Krow + kt;
        const bf16* Bg = B + (long)colB0 * Krow + kt;
        #pragma unroll
        for (int i = 0; i < 4; i++) {
            int seg = wid * 4 + i;
            int r = seg * 8 + rsub;
            gload_lds16(&Ag[(long)r * Krow + csub], &As[seg * 512]);
            gload_lds16(&Bg[(long)r * Krow + csub], &Bs[seg * 512]);
        }
        __syncthreads();
        #pragma unroll
        for (int kk = 0; kk < 2; kk++) {
            bf16x8 af[4], bfr[4];
            int ko = (kk * 32 + (lane >> 4) * 8) ^ rdsw;
            #pragma unroll
            for (int m = 0; m < 4; m++) af[m]  = *(const bf16x8*)&As[(wm + m * 16 + (lane & 15)) * 64 + ko];
            #pragma unroll
            for (int n = 0; n < 4; n++) bfr[n] = *(const bf16x8*)&Bs[(wn + n * 16 + (lane & 15)) * 64 + ko];
            #pragma unroll
            for (int m = 0; m < 4; m++)
                #pragma unroll
                for (int n = 0; n < 4; n++)
                    acc[m][n] = __builtin_amdgcn_mfma_f32_16x16x32_bf16(af[m], bfr[n], acc[m][n], 0, 0, 0);
        }
        __syncthreads();
    }
    #pragma unroll
    for (int m = 0; m < 4; m++) {
        #pragma unroll
        for (int n = 0; n < 4; n++) {
            #pragma unroll
            for (int j = 0; j < 4; j++) {
                int row = rowA0 + wm + m * 16 + (lane >> 4) * 4 + j;
                int col = colB0 + wn + n * 16 + (lane & 15);
                float v = acc[m][n][j];
                if (EPI == EPI_F32) {
                    Cf[(long)row * N + col] = v;        // z-offsets already applied
                } else if (EPI == EPI_BF16) {
                    Cb[(long)row * N + col] = (bf16)(v * scale);
                } else if (EPI == EPI_VT) {
                    int b = row >> 11, k = row & 2047;
                    Cb[((long)b * 512 + col) * 2048 + k] = (bf16)v;
                } else if (EPI == EPI_BIAS_RELU_BF16) {
                    float y = fmaxf(v + bias[col], 0.0f);
                    Cb[(long)row * N + col] = (bf16)y;
                } else if (EPI == EPI_BIAS_F32) {
                    Cf[(long)row * N + col] = v + bias[col];
                }
            }
        }
    }
}

// ---------------------------------------------------------------- 256^2 deep-pipeline GEMM (BK=64)
template<int EPI, bool XCD, bool CSKIP, int BANDW, int NT>
__global__ __launch_bounds__(512)
void gemm256(const bf16* __restrict__ A, const bf16* __restrict__ B,
             float* __restrict__ Cf, bf16* __restrict__ Cb,
             const float* __restrict__ bias, int N, int K,
             long sA, long sB, long sC) {
    int br, bc;
    if (XCD) {
        int nwg = gridDim.x * gridDim.y;          // caller ensures %8==0
        int lin = blockIdx.y * gridDim.x + blockIdx.x;
        lin = (lin & 7) * (nwg >> 3) + (lin >> 3);
        if (BANDW > 0) {
            int per = BANDW * gridDim.y;          // blocks per band
            int band = lin / per, w2 = lin - band * per;
            br = w2 / BANDW; bc = band * BANDW + (w2 - br * BANDW);
        } else {
            br = lin / gridDim.x; bc = lin - br * gridDim.x;
        }
    } else { br = blockIdx.y; bc = blockIdx.x; }
    if (CSKIP && bc > br) return;                 // causal skip at 256-tile granularity
    int z = blockIdx.z;
    A  += (long)z * sA;
    B  += (long)z * sB;
    Cf += (long)z * sC;
    __shared__ bf16 lds[2][2][256 * 64];          // [buf][A/B] = 128 KiB
    int tid = threadIdx.x;
    int lane = tid & 63, wid = tid >> 6;
    int wm2 = wid >> 2, wn4 = wid & 3;
    long rowA0 = (long)br * 256, colB0 = (long)bc * 256;
    int rsub = lane >> 3;
    int csw  = ((lane & 7) ^ rsub) * 8;           // pre-swizzled source col
    int l15 = lane & 15;
    int rdxor = (lane & 7) << 3;
    int kbase = (lane >> 4) * 8;
    const bf16* Abase = A + rowA0 * K;
    const bf16* Bbase = B + colB0 * K;
    f32x4 acc[8][4] = {};

    auto stage = [&](int t) {
        int buf = t & 1;
        const bf16* Ag = Abase + t * 64;
        const bf16* Bg = Bbase + t * 64;
        #pragma unroll
        for (int i = 0; i < 4; i++) {
            int seg = wid * 4 + i;                // 0..31
            long r = seg * 8 + rsub;
            gload_lds16(&Ag[r * K + csw], &lds[buf][0][seg * 512]);
        }
        #pragma unroll
        for (int i = 0; i < 4; i++) {
            int seg = wid * 4 + i;
            long r = seg * 8 + rsub;
            gload_lds16(&Bg[r * K + csw], &lds[buf][1][seg * 512]);
        }
    };

    stage(0);
    stage(1);

    for (int t = 0; t < NT; t++) {
        int buf = t & 1;
        if (t == NT - 1) asm volatile("s_waitcnt vmcnt(0)" ::: "memory");
        else             asm volatile("s_waitcnt vmcnt(8)" ::: "memory");
        __builtin_amdgcn_s_barrier();             // everyone's tile-t data visible
        const bf16* As = lds[buf][0];
        const bf16* Bs = lds[buf][1];
        bf16x8 bfr[2][4], af[2][4];
        #pragma unroll
        for (int kk = 0; kk < 2; kk++)
            #pragma unroll
            for (int n = 0; n < 4; n++) {
                int r = wn4 * 64 + n * 16 + l15;
                bfr[kk][n] = *(const bf16x8*)&Bs[r * 64 + ((kk * 32 + kbase) ^ rdxor)];
            }
        #pragma unroll
        for (int kk = 0; kk < 2; kk++)
            #pragma unroll
            for (int m = 0; m < 4; m++) {
                int r = wm2 * 128 + m * 16 + l15;
                af[kk][m] = *(const bf16x8*)&As[r * 64 + ((kk * 32 + kbase) ^ rdxor)];
            }
        __builtin_amdgcn_s_setprio(1);
        #pragma unroll
        for (int kk = 0; kk < 2; kk++)
            #pragma unroll
            for (int m = 0; m < 4; m++)
                #pragma unroll
                for (int n = 0; n < 4; n++)
                    acc[m][n] = __builtin_amdgcn_mfma_f32_16x16x32_bf16(af[kk][m], bfr[kk][n], acc[m][n], 0, 0, 0);
        __builtin_amdgcn_s_setprio(0);
        // second half of A rows
        #pragma unroll
        for (int kk = 0; kk < 2; kk++)
            #pragma unroll
            for (int m = 0; m < 4; m++) {
                int r = wm2 * 128 + 64 + m * 16 + l15;
                af[kk][m] = *(const bf16x8*)&As[r * 64 + ((kk * 32 + kbase) ^ rdxor)];
            }
        asm volatile("s_waitcnt lgkmcnt(0)" ::: "memory"); // all my buf reads done
        __builtin_amdgcn_sched_barrier(0);
        __builtin_amdgcn_s_barrier();             // ALL waves done reading buf
        if (t + 2 < NT) stage(t + 2);             // overwrite buf; flies across iters
        __builtin_amdgcn_s_setprio(1);
        #pragma unroll
        for (int kk = 0; kk < 2; kk++)
            #pragma unroll
            for (int m = 0; m < 4; m++)
                #pragma unroll
                for (int n = 0; n < 4; n++)
                    acc[4 + m][n] = __builtin_amdgcn_mfma_f32_16x16x32_bf16(af[kk][m], bfr[kk][n], acc[4 + m][n], 0, 0, 0);
        __builtin_amdgcn_s_setprio(0);
    }

    if constexpr (EPI == EPI_QKV) {
        // N=1536; 256-col panels are block-uniform: 0-1=Q, 2-3=K, 4-5=V.
        int region = (int)(colB0 >> 9);           // 0=Q, 1=K, 2=V
        if (region < 2) {
            bf16* dst = Cb + (long)region * (8192L * 512);
            int cb = ((int)colB0 & 511) + wn4 * 64;
            #pragma unroll
            for (int m = 0; m < 8; m++)
                #pragma unroll
                for (int n = 0; n < 4; n++)
                    #pragma unroll
                    for (int j = 0; j < 4; j++) {
                        long row = rowA0 + wm2 * 128 + m * 16 + (lane >> 4) * 4 + j;
                        int c = cb + n * 16 + l15;
                        dst[row * 512 + c] = (bf16)acc[m][n][j];
                    }
        } else {
            bf16* vtb = Cb + 2L * 8192 * 512;
            int cb = ((int)colB0 - 1024) + wn4 * 64;
            #pragma unroll
            for (int m = 0; m < 8; m++)
                #pragma unroll
                for (int n = 0; n < 4; n++) {
                    long k0 = rowA0 + wm2 * 128 + m * 16 + (lane >> 4) * 4;
                    long b = k0 >> 11, k = k0 & 2047;
                    int c = cb + n * 16 + l15;
                    bf16x4 pk = { (bf16)acc[m][n][0], (bf16)acc[m][n][1],
                                  (bf16)acc[m][n][2], (bf16)acc[m][n][3] };
                    *(bf16x4*)&vtb[(b * 512 + c) * 2048 + k] = pk;
                }
        }
    } else {
        #pragma unroll
        for (int m = 0; m < 8; m++) {
            #pragma unroll
            for (int n = 0; n < 4; n++) {
                #pragma unroll
                for (int j = 0; j < 4; j++) {
                    long row = rowA0 + wm2 * 128 + m * 16 + (lane >> 4) * 4 + j;
                    long col = colB0 + wn4 * 64 + n * 16 + l15;
                    float v = acc[m][n][j];
                    if (EPI == EPI_BIAS_F32) {
                        Cf[row * N + col] = v + bias[col];
                    } else if (EPI == EPI_BIAS_F32_NT) {
                        __builtin_nontemporal_store(v + bias[col], &Cf[row * N + col]);
                    } else if (EPI == EPI_BIAS_RELU_BF16) {
                        Cb[row * N + col] = (bf16)fmaxf(v + bias[col], 0.0f);
                    } else if (EPI == EPI_F32) {
                        Cf[row * N + col] = v;
                    }
                }
            }
        }
    }
}

// ---------------------------------------------------------------- vocab GEMM (R8 proven)
template<int BANDB>
__global__ __launch_bounds__(256)
void gemm128v(const bf16* __restrict__ A, const bf16* __restrict__ B,
              float* __restrict__ C, const float* __restrict__ bias,
              int N, int K) {
    const int NBR = 64;                            // 8192/128 row-tiles
    const int NT  = 8;                             // K=512 / 64
    int nwg = gridDim.x;                           // 16000 (%8==0)
    int lin = blockIdx.x;
    lin = (lin & 7) * (nwg >> 3) + (lin >> 3);     // XCD-contiguous chunks
    int per = BANDB * NBR;
    int band = lin / per, w2 = lin - band * per;
    int br = w2 / BANDB, bc = band * BANDB + (w2 - br * BANDB);

    __shared__ bf16 lds[2][2][128 * 64];           // 64 KiB -> 2 blocks/CU
    int tid = threadIdx.x;
    int lane = tid & 63, wid = tid >> 6;
    int wm = (wid >> 1) * 64, wn = (wid & 1) * 64;
    int rsub = lane >> 3;
    int csub = ((lane & 7) ^ rsub) * 8;            // pre-swizzled source col
    int rdsw = (lane & 7) * 8;                     // read-side XOR
    long rowA0 = (long)br * 128, colB0 = (long)bc * 128;
    const bf16* Abase = A + rowA0 * K;
    const bf16* Bbase = B + colB0 * K;
    f32x4 acc[4][4] = {};

    auto stage = [&](int t) {                      // 8 VMEM issues/thread
        int buf = t & 1;
        const bf16* Ag = Abase + t * 64;
        const bf16* Bg = Bbase + t * 64;
        #pragma unroll
        for (int i = 0; i < 4; i++) {
            int seg = wid * 4 + i;                 // 0..15
            long r = seg * 8 + rsub;
            gload_lds16(&Ag[r * K + csub], &lds[buf][0][seg * 512]);
        }
        #pragma unroll
        for (int i = 0; i < 4; i++) {
            int seg = wid * 4 + i;
            long r = seg * 8 + rsub;
            gload_lds16(&Bg[r * K + csub], &lds[buf][1][seg * 512]);
        }
    };

    stage(0);
    stage(1);

    for (int t = 0; t < NT; t++) {
        int buf = t & 1;
        if (t == NT - 1) asm volatile("s_waitcnt vmcnt(0)" ::: "memory");
        else             asm volatile("s_waitcnt vmcnt(8)" ::: "memory");
        __builtin_amdgcn_s_barrier();              // tile-t data visible
        const bf16* As = lds[buf][0];
        const bf16* Bs = lds[buf][1];
        __builtin_amdgcn_s_setprio(1);
        #pragma unroll
        for (int kk = 0; kk < 2; kk++) {
            bf16x8 af[4], bfr[4];
            int ko = (kk * 32 + (lane >> 4) * 8) ^ rdsw;
            #pragma unroll
            for (int m = 0; m < 4; m++) af[m]  = *(const bf16x8*)&As[(wm + m * 16 + (lane & 15)) * 64 + ko];
            #pragma unroll
            for (int n = 0; n < 4; n++) bfr[n] = *(const bf16x8*)&Bs[(wn + n * 16 + (lane & 15)) * 64 + ko];
            #pragma unroll
            for (int m = 0; m < 4; m++)
                #pragma unroll
                for (int n = 0; n < 4; n++)
                    acc[m][n] = __builtin_amdgcn_mfma_f32_16x16x32_bf16(af[m], bfr[n], acc[m][n], 0, 0, 0);
        }
        __builtin_amdgcn_s_setprio(0);
        asm volatile("s_waitcnt lgkmcnt(0)" ::: "memory"); // my buf reads done
        __builtin_amdgcn_sched_barrier(0);
        __builtin_amdgcn_s_barrier();              // ALL waves done reading buf
        if (t + 2 < NT) stage(t + 2);              // overwrite buf
    }

    #pragma unroll
    for (int m = 0; m < 4; m++) {
        #pragma unroll
        for (int n = 0; n < 4; n++) {
            int col = (int)colB0 + wn + n * 16 + (lane & 15);
            float bcol = bias[col];
            #pragma unroll
            for (int j = 0; j < 4; j++) {
                long row = rowA0 + wm + m * 16 + (lane >> 4) * 4 + j;
                __builtin_nontemporal_store(acc[m][n][j] + bcol, &C[row * N + col]);
            }
        }
    }
}

// ---------------------------------------------------------------- launch
extern "C" void kernel_launch(void* const* d_in, const int* in_sizes, int n_in,
                              void* d_out, int out_size, void* d_ws, size_t ws_size,
                              hipStream_t stream) {
    const int*   x       = (const int*)d_in[0];
    const float* word_emb = (const float*)d_in[1];
    const float* pos_emb  = (const float*)d_in[2];
    const float* Wq = (const float*)d_in[3];
    const float* Wk = (const float*)d_in[4];
    const float* Wv = (const float*)d_in[5];
    const float* g1 = (const float*)d_in[6];
    const float* b1 = (const float*)d_in[7];
    const float* w_ffn1 = (const float*)d_in[8];
    const float* b_ffn1 = (const float*)d_in[9];
    const float* w_ffn2 = (const float*)d_in[10];
    const float* b_ffn2 = (const float*)d_in[11];
    const float* g2 = (const float*)d_in[12];
    const float* b2 = (const float*)d_in[13];
    const float* w_vocab = (const float*)d_in[14];
    const float* b_vocab = (const float*)d_in[15];
    float* out = (float*)d_out;

    char* w = (char*)d_ws;
    auto alloc = [&](size_t bytes) { char* p = w; w += (bytes + 255) & ~255ULL; return p; };
    // NOTE: wqb/wkb/wvb must stay contiguous ([1536 x 512] fused weight);
    //       qb/kb/vt contiguous (EPI_QKV writes all three off qb);
    //       ctx/pv1/pv2/pv3 contiguous (ZB_PV chunk offset = 8192*512 floats);
    //       ffn2f/ffn2b contiguous (split-K sC = 8192*512 floats).
    bf16* wqb   = (bf16*)alloc(512 * 512 * 2);
    bf16* wkb   = (bf16*)alloc(512 * 512 * 2);
    bf16* wvb   = (bf16*)alloc(512 * 512 * 2);
    bf16* w1b   = (bf16*)alloc(2048 * 512 * 2);
    bf16* w2b   = (bf16*)alloc(512 * 2048 * 2);
    bf16* wvocb = (bf16*)alloc((size_t)32000 * 512 * 2);
    float* embf = (float*)alloc((size_t)8192 * 512 * 4);
    bf16* embb  = (bf16*)alloc((size_t)8192 * 512 * 2);   // also final_b (aliased)
    bf16* qb    = (bf16*)alloc((size_t)8192 * 512 * 2);
    bf16* kb    = (bf16*)alloc((size_t)8192 * 512 * 2);   // also out1_b (aliased)
    bf16* vt    = (bf16*)alloc((size_t)8192 * 512 * 2);
    bf16* scoresb = (bf16*)alloc((size_t)4 * 2048 * 2048 * 2); // bf16 scores; also ffn1_b
    bf16* probs = (bf16*)alloc((size_t)4 * 2048 * 2048 * 2);
    float* ctx  = (float*)alloc((size_t)8192 * 512 * 4);  // pv0
    float* pv1  = (float*)alloc((size_t)8192 * 512 * 4);  // pv chunk-1 partial
    float* pv2  = (float*)alloc((size_t)8192 * 512 * 4);  // pv chunk-2 partial
    float* pv3  = (float*)alloc((size_t)8192 * 512 * 4);  // pv chunk-3 partial
    float* out1f = (float*)alloc((size_t)8192 * 512 * 4);
    float* ffn2f = (float*)alloc((size_t)8192 * 512 * 4); // ffn2 chunk-0 partial
    float* ffn2b = (float*)alloc((size_t)8192 * 512 * 4); // ffn2 chunk-1 partial
    bf16* ffn1b = scoresb;         // alias: scores dead after softmax
    bf16* out1b = kb;              // alias: kb dead after scores GEMM
    bf16* finalb = embb;           // alias: embb dead after QKV GEMM
    (void)pv2; (void)pv3;

    const float qscale = 0.044194173824159216f; // 1/sqrt(512)

    // merged: embedding (blocks 0..4095) + all six weight cvts (blocks 4096..5631)
    CvtArgs ca;
    ca.src[0] = Wq;      ca.dst[0] = wqb;   ca.n4[0] = 512 * 512 / 4;          ca.scale[0] = qscale;
    ca.src[1] = Wk;      ca.dst[1] = wkb;   ca.n4[1] = 512 * 512 / 4;          ca.scale[1] = 1.0f;
    ca.src[2] = Wv;      ca.dst[2] = wvb;   ca.n4[2] = 512 * 512 / 4;          ca.scale[2] = 1.0f;
    ca.src[3] = w_ffn1;  ca.dst[3] = w1b;   ca.n4[3] = 2048 * 512 / 4;         ca.scale[3] = 1.0f;
    ca.src[4] = w_ffn2;  ca.dst[4] = w2b;   ca.n4[4] = 512 * 2048 / 4;         ca.scale[4] = 1.0f;
    ca.src[5] = w_vocab; ca.dst[5] = wvocb; ca.n4[5] = (long)32000 * 512 / 4;  ca.scale[5] = 1.0f;
    embed_cvt<<<5632, 256, 0, stream>>>(ca, x, word_emb, pos_emb, embf, embb);

    // fused Q|K|V projection: emb[8192x512] @ Wqkv^T[1536x512] -> qb,kb,vt
    gemm256<EPI_QKV, true, false, 0, 8><<<dim3(6, 32, 1), 512, 0, stream>>>(
        embb, wqb, nullptr, qb, nullptr, 1536, 512, 0, 0, 0);

    // scores = Q @ K^T: 128^2 tiles, causal skip, bf16 output (scores are tiny,
    // |s|~4e-3: bf16 rounding is ~100x below the existing error floor) —
    // halves scores write + softmax read traffic.
    gemm_bt<EPI_BF16, true, false, false, ZB_BATCH><<<dim3(16, 16, 4), 256, 0, stream>>>(
        qb, kb, nullptr, scoresb, nullptr, 1.0f, 2048, 2048, 512, 512,
        (long)2048 * 512, (long)2048 * 512, (long)2048 * 2048);

    softmax_causal<<<8192, 256, 0, stream>>>(scoresb, probs);

    // context = P @ V, split-K x4 without atomics: chunk c covers k in
    // [c*512, min(keff, c*512+512)) -> pv0..pv3; summed inside ln1.
    gemm_bt<EPI_F32, false, false, false, ZB_PV><<<dim3(4, 16, 16), 256, 0, stream>>>(
        probs, vt, ctx, nullptr, nullptr, 1.0f, 2048, 512, 2048, 2048,
        (long)2048 * 2048, (long)512 * 2048, (long)2048 * 512);

    // ln1: residual = embf + pv0 (+ pv1/pv2/pv3 row-conditionally)
    ln_kernel<true, 1, false><<<8192, 128, 0, stream>>>(
        embf, ctx, pv1, nullptr, g1, b1, out1f, out1b);

    // ffn1 = relu(out1 @ W1^T + b1)  -- 256^2 deep pipeline
    gemm256<EPI_BIAS_RELU_BF16, true, false, 0, 8><<<dim3(8, 32, 1), 512, 0, stream>>>(
        out1b, w1b, nullptr, ffn1b, b_ffn1, 2048, 512, 0, 0, 0);

    // ffn2 = ffn1 @ W2^T, split-K x2 without atomics: chunk z covers K cols
    // [z*1024, z*1024+1024) -> ffn2f/ffn2b; summed (+b_ffn2) inside ln2.
    gemm_bt<EPI_F32, false, false, false, ZB_BATCH><<<dim3(4, 64, 2), 256, 0, stream>>>(
        ffn1b, w2b, ffn2f, nullptr, nullptr, 1.0f, 8192, 512, 1024, 2048,
        1024, 1024, 8192L * 512);

    // ln2: residual = out1f + ffn2f + ffn2b + b_ffn2
    ln_kernel<false, 2, true><<<8192, 128, 0, stream>>>(
        out1f, ffn2f, ffn2b, b_ffn2, g2, b2, nullptr, finalb);

    // logits = final @ w_vocab^T + b_vocab  -- 128^2 double-buffered pipeline,
    // 2 blocks/CU, 25 bands of 10 bc-tiles, NT stores (R8 proven).
    gemm128v<10><<<16000, 256, 0, stream>>>(finalb, wvocb, out, b_vocab, 32000, 512);
}

// Round 13
// 504.123 us; speedup vs baseline: 1.1126x; 1.0482x over previous
//
#include <hip/hip_runtime.h>
#include <hip/hip_bf16.h>

typedef __bf16 bf16;
typedef __attribute__((ext_vector_type(4))) __bf16 bf16x4;
typedef __attribute__((ext_vector_type(8))) __bf16 bf16x8;
typedef __attribute__((ext_vector_type(4))) float f32x4;

__device__ inline void gload_lds16(const bf16* g, bf16* l) {
    __builtin_amdgcn_global_load_lds(
        (const __attribute__((address_space(1))) void*)g,
        (__attribute__((address_space(3))) void*)l, 16, 0, 0);
}

// ---------------------------------------------------------------- embed + weight cvt (merged)
struct CvtArgs {
    const float* src[6];
    bf16* dst[6];
    long n4[6];
    float scale[6];
};
// blocks 0..4095: embedding (2 rows each, bf16 only); 4096..5631: 6x256 cvt blocks.
__global__ void embed_cvt(CvtArgs a, const int* __restrict__ x,
                          const float* __restrict__ we, const float* __restrict__ pe,
                          bf16* __restrict__ emb_b) {
    int b = blockIdx.x;
    int tid = threadIdx.x;           // 256
    if (b < 4096) {
        int row = b * 2 + (tid >> 7);
        int c = tid & 127;
        int tok = x[row];
        int s = row & 2047;
        float4 w = ((const float4*)we)[(long)tok * 128 + c];
        float4 p = ((const float4*)pe)[(long)s * 128 + c];
        bf16x4 eb = { (bf16)(w.x + p.x), (bf16)(w.y + p.y),
                      (bf16)(w.z + p.z), (bf16)(w.w + p.w) };
        ((bf16x4*)emb_b)[(long)row * 128 + c] = eb;
    } else {
        int bb = b - 4096;           // 0..1535
        int j  = bb >> 8;            // tensor 0..5
        int bx = bb & 255;
        const float* __restrict__ src = a.src[j];
        bf16* __restrict__ dst = a.dst[j];
        long n4 = a.n4[j];
        float sc = a.scale[j];
        long i = (long)bx * 256 + tid;
        long stride = 256 * 256;
        for (; i < n4; i += stride) {
            float4 v = ((const float4*)src)[i];
            bf16x4 o = { (bf16)(v.x * sc), (bf16)(v.y * sc), (bf16)(v.z * sc), (bf16)(v.w * sc) };
            ((bf16x4*)dst)[i] = o;
        }
    }
}

// ---------------------------------------------------------------- layernorm (bf16 trunk + partials)
// Residual = a + partials [+ rb(col bias)], all bf16 inputs, f32 math.
// C3: 1 = PV split-K x4: add c[k] (k=0..3, stride 8192*512 bf16) with k=0
//         always, k>=1 only for rows with (row&2047) >= k*512;
//     2 = ffn2 split-K x2: add c[0], c[1] always.
template<int C3, bool RBIAS>
__global__ void ln_kernel(const bf16* __restrict__ a, const bf16* __restrict__ c,
                          const float* __restrict__ rb,
                          const float* __restrict__ g, const float* __restrict__ bb,
                          bf16* __restrict__ ob) {
    int row = blockIdx.x;            // 8192
    int t   = threadIdx.x;           // 128
    bf16x4 av = ((const bf16x4*)a)[(long)row * 128 + t];
    float4 xv = { (float)av[0], (float)av[1], (float)av[2], (float)av[3] };
    if (C3 == 1) {
        int r = row & 2047;
        #pragma unroll
        for (int k = 0; k < 4; k++) {
            if (k == 0 || r >= k * 512) {
                bf16x4 cv = ((const bf16x4*)(c + (long)k * 8192 * 512))[(long)row * 128 + t];
                xv.x += (float)cv[0]; xv.y += (float)cv[1];
                xv.z += (float)cv[2]; xv.w += (float)cv[3];
            }
        }
    } else if (C3 == 2) {
        #pragma unroll
        for (int k = 0; k < 2; k++) {
            bf16x4 cv = ((const bf16x4*)(c + (long)k * 8192 * 512))[(long)row * 128 + t];
            xv.x += (float)cv[0]; xv.y += (float)cv[1];
            xv.z += (float)cv[2]; xv.w += (float)cv[3];
        }
    }
    if (RBIAS) {
        float4 rv = ((const float4*)rb)[t];
        xv.x += rv.x; xv.y += rv.y; xv.z += rv.z; xv.w += rv.w;
    }
    float s  = xv.x + xv.y + xv.z + xv.w;
    float sq = xv.x * xv.x + xv.y * xv.y + xv.z * xv.z + xv.w * xv.w;
    #pragma unroll
    for (int o = 32; o > 0; o >>= 1) {
        s  += __shfl_xor(s, o);
        sq += __shfl_xor(sq, o);
    }
    __shared__ float rs[2], rq[2];
    int wid = t >> 6;
    if ((t & 63) == 0) { rs[wid] = s; rq[wid] = sq; }
    __syncthreads();
    s = rs[0] + rs[1]; sq = rq[0] + rq[1];
    float mu   = s * (1.0f / 512.0f);
    float var  = sq * (1.0f / 512.0f) - mu * mu;
    float rstd = rsqrtf(var + 1e-5f);
    float4 gv = ((const float4*)g)[t];
    float4 bv = ((const float4*)bb)[t];
    bf16x4 yb = { (bf16)((xv.x - mu) * rstd * gv.x + bv.x),
                  (bf16)((xv.y - mu) * rstd * gv.y + bv.y),
                  (bf16)((xv.z - mu) * rstd * gv.z + bv.z),
                  (bf16)((xv.w - mu) * rstd * gv.w + bv.w) };
    ((bf16x4*)ob)[(long)row * 128 + t] = yb;
}

// ---------------------------------------------------------------- causal softmax (bf16 scores)
__global__ void softmax_causal(const bf16* __restrict__ sc, bf16* __restrict__ pr) {
    int row = blockIdx.x;            // 8192
    int z = row >> 11, q = row & 2047;
    const bf16* srow = sc + ((long)z * 2048 + q) * 2048;
    bf16*       prow = pr + ((long)z * 2048 + q) * 2048;
    int t = threadIdx.x;             // 256, each handles 8 cols
    float v[8];
    int c0 = t * 8;
    if (t <= (q >> 3)) {
        bf16x8 vb = *(const bf16x8*)&srow[c0];
        #pragma unroll
        for (int j = 0; j < 8; j++) v[j] = (float)vb[j];
    } else {
        #pragma unroll
        for (int j = 0; j < 8; j++) v[j] = -1e30f;
    }
    float mx = -1e30f;
    #pragma unroll
    for (int j = 0; j < 8; j++) {
        if (c0 + j > q) v[j] = -1e30f;
        mx = fmaxf(mx, v[j]);
    }
    int lane = t & 63, wid = t >> 6;
    #pragma unroll
    for (int o = 32; o > 0; o >>= 1) mx = fmaxf(mx, __shfl_xor(mx, o));
    __shared__ float redm[4], reds[4];
    if (lane == 0) redm[wid] = mx;
    __syncthreads();
    mx = fmaxf(fmaxf(redm[0], redm[1]), fmaxf(redm[2], redm[3]));
    float p[8]; float sum = 0.f;
    #pragma unroll
    for (int j = 0; j < 8; j++) {
        p[j] = (c0 + j <= q) ? __expf(v[j] - mx) : 0.f;
        sum += p[j];
    }
    #pragma unroll
    for (int o = 32; o > 0; o >>= 1) sum += __shfl_xor(sum, o);
    if (lane == 0) reds[wid] = sum;
    __syncthreads();
    sum = reds[0] + reds[1] + reds[2] + reds[3];
    float inv = 1.0f / sum;
    int wlim = ((q >> 7) + 1) * 128;             // causal 128-block boundary
    if (c0 < wlim) {
        bf16x8 o;
        #pragma unroll
        for (int j = 0; j < 8; j++) o[j] = (bf16)(p[j] * inv);
        *(bf16x8*)&prow[c0] = o;
    }
}

// ---------------------------------------------------------------- epilogue tags
enum { EPI_F32 = 0, EPI_BF16 = 1, EPI_VT = 2, EPI_BIAS_RELU_BF16 = 3, EPI_BIAS_F32 = 4,
       EPI_QKV = 5, EPI_BIAS_F32_NT = 6 };
enum { ZB_BATCH = 0, ZB_PV = 1 };

// ---------------------------------------------------------------- 128^2 GEMM (proven)
// ZB_BATCH: z = batch (or K-chunk); A/B/Cf/Cb shifted by z*sA/sB/sC elements.
// ZB_PV   : z = batch*4 + chunk. Causal P@V with split-K chunks of 512:
//           chunk c covers k in [c*512, min(keff, c*512+512)).
//           C base for chunk c is +c*8192*512 (pv0..pv3 contiguous);
//           blocks whose causal keff <= lo exit early (block-uniform).
template<int EPI, bool CAUSAL_SKIP, bool CAUSAL_K, bool XCD, int ZMODE>
__global__ __launch_bounds__(256)
void gemm_bt(const bf16* __restrict__ A, const bf16* __restrict__ B,
             float* __restrict__ Cf, bf16* __restrict__ Cb,
             const float* __restrict__ bias, float scale,
             int M, int N, int K, int Krow, long sA, long sB, long sC) {
    int br, bc;
    if (XCD) {
        int nwg = gridDim.x * gridDim.y;         // caller ensures %8==0
        int lin = blockIdx.y * gridDim.x + blockIdx.x;
        lin = (lin & 7) * (nwg >> 3) + (lin >> 3);
        br = lin / gridDim.x; bc = lin - br * gridDim.x;
    } else { br = blockIdx.y; bc = blockIdx.x; }
    int z = blockIdx.z;
    int Kext = K;
    if (ZMODE == ZB_BATCH) {
        A += (long)z * sA; B += (long)z * sB; Cf += (long)z * sC; Cb += (long)z * sC;
    } else if (ZMODE == ZB_PV) {
        int batch = z >> 2, chunk = z & 3;
        A += (long)batch * sA; B += (long)batch * sB;
        Cf += (long)chunk * (8192L * 512) + (long)batch * sC;
        Cb += (long)chunk * (8192L * 512) + (long)batch * sC;
        int keff = min(K, (br + 1) * 128);
        int lo = chunk * 512;
        if (keff <= lo) return;                  // block-uniform early exit
        A += lo; B += lo;
        Kext = min(keff, lo + 512) - lo;
    }
    if (CAUSAL_SKIP && bc > br) return;
    if (CAUSAL_K) Kext = min(Kext, (br + 1) * 128);
    __shared__ bf16 As[128 * 64];
    __shared__ bf16 Bs[128 * 64];
    int tid = threadIdx.x;
    int lane = tid & 63, wid = tid >> 6;
    int wm = (wid >> 1) * 64, wn = (wid & 1) * 64;
    f32x4 acc[4][4] = {};
    int rowA0 = br * 128, colB0 = bc * 128;
    int rsub = lane >> 3;
    int csub = ((lane & 7) ^ rsub) * 8;            // pre-swizzled source col
    int rdsw = (lane & 7) * 8;                     // read-side XOR
    for (int kt = 0; kt < Kext; kt += 64) {
        const bf16* Ag = A + (long)rowA0 * Krow + kt;
        const bf16* Bg = B + (long)colB0 * Krow + kt;
        #pragma unroll
        for (int i = 0; i < 4; i++) {
            int seg = wid * 4 + i;
            int r = seg * 8 + rsub;
            gload_lds16(&Ag[(long)r * Krow + csub], &As[seg * 512]);
            gload_lds16(&Bg[(long)r * Krow + csub], &Bs[seg * 512]);
        }
        __syncthreads();
        #pragma unroll
        for (int kk = 0; kk < 2; kk++) {
            bf16x8 af[4], bfr[4];
            int ko = (kk * 32 + (lane >> 4) * 8) ^ rdsw;
            #pragma unroll
            for (int m = 0; m < 4; m++) af[m]  = *(const bf16x8*)&As[(wm + m * 16 + (lane & 15)) * 64 + ko];
            #pragma unroll
            for (int n = 0; n < 4; n++) bfr[n] = *(const bf16x8*)&Bs[(wn + n * 16 + (lane & 15)) * 64 + ko];
            #pragma unroll
            for (int m = 0; m < 4; m++)
                #pragma unroll
                for (int n = 0; n < 4; n++)
                    acc[m][n] = __builtin_amdgcn_mfma_f32_16x16x32_bf16(af[m], bfr[n], acc[m][n], 0, 0, 0);
        }
        __syncthreads();
    }
    #pragma unroll
    for (int m = 0; m < 4; m++) {
        #pragma unroll
        for (int n = 0; n < 4; n++) {
            #pragma unroll
            for (int j = 0; j < 4; j++) {
                int row = rowA0 + wm + m * 16 + (lane >> 4) * 4 + j;
                int col = colB0 + wn + n * 16 + (lane & 15);
                float v = acc[m][n][j];
                if (EPI == EPI_F32) {
                    Cf[(long)row * N + col] = v;        // z-offsets already applied
                } else if (EPI == EPI_BF16) {
                    Cb[(long)row * N + col] = (bf16)(v * scale);
                } else if (EPI == EPI_VT) {
                    int b = row >> 11, k = row & 2047;
                    Cb[((long)b * 512 + col) * 2048 + k] = (bf16)v;
                } else if (EPI == EPI_BIAS_RELU_BF16) {
                    float y = fmaxf(v + bias[col], 0.0f);
                    Cb[(long)row * N + col] = (bf16)y;
                } else if (EPI == EPI_BIAS_F32) {
                    Cf[(long)row * N + col] = v + bias[col];
                }
            }
        }
    }
}

// ---------------------------------------------------------------- 256^2 deep-pipeline GEMM (BK=64)
template<int EPI, bool XCD, bool CSKIP, int BANDW, int NT>
__global__ __launch_bounds__(512)
void gemm256(const bf16* __restrict__ A, const bf16* __restrict__ B,
             float* __restrict__ Cf, bf16* __restrict__ Cb,
             const float* __restrict__ bias, int N, int K,
             long sA, long sB, long sC) {
    int br, bc;
    if (XCD) {
        int nwg = gridDim.x * gridDim.y;          // caller ensures %8==0
        int lin = blockIdx.y * gridDim.x + blockIdx.x;
        lin = (lin & 7) * (nwg >> 3) + (lin >> 3);
        if (BANDW > 0) {
            int per = BANDW * gridDim.y;          // blocks per band
            int band = lin / per, w2 = lin - band * per;
            br = w2 / BANDW; bc = band * BANDW + (w2 - br * BANDW);
        } else {
            br = lin / gridDim.x; bc = lin - br * gridDim.x;
        }
    } else { br = blockIdx.y; bc = blockIdx.x; }
    if (CSKIP && bc > br) return;                 // causal skip at 256-tile granularity
    int z = blockIdx.z;
    A  += (long)z * sA;
    B  += (long)z * sB;
    Cf += (long)z * sC;
    __shared__ bf16 lds[2][2][256 * 64];          // [buf][A/B] = 128 KiB
    int tid = threadIdx.x;
    int lane = tid & 63, wid = tid >> 6;
    int wm2 = wid >> 2, wn4 = wid & 3;
    long rowA0 = (long)br * 256, colB0 = (long)bc * 256;
    int rsub = lane >> 3;
    int csw  = ((lane & 7) ^ rsub) * 8;           // pre-swizzled source col
    int l15 = lane & 15;
    int rdxor = (lane & 7) << 3;
    int kbase = (lane >> 4) * 8;
    const bf16* Abase = A + rowA0 * K;
    const bf16* Bbase = B + colB0 * K;
    f32x4 acc[8][4] = {};

    auto stage = [&](int t) {
        int buf = t & 1;
        const bf16* Ag = Abase + t * 64;
        const bf16* Bg = Bbase + t * 64;
        #pragma unroll
        for (int i = 0; i < 4; i++) {
            int seg = wid * 4 + i;                // 0..31
            long r = seg * 8 + rsub;
            gload_lds16(&Ag[r * K + csw], &lds[buf][0][seg * 512]);
        }
        #pragma unroll
        for (int i = 0; i < 4; i++) {
            int seg = wid * 4 + i;
            long r = seg * 8 + rsub;
            gload_lds16(&Bg[r * K + csw], &lds[buf][1][seg * 512]);
        }
    };

    stage(0);
    stage(1);

    for (int t = 0; t < NT; t++) {
        int buf = t & 1;
        if (t == NT - 1) asm volatile("s_waitcnt vmcnt(0)" ::: "memory");
        else             asm volatile("s_waitcnt vmcnt(8)" ::: "memory");
        __builtin_amdgcn_s_barrier();             // everyone's tile-t data visible
        const bf16* As = lds[buf][0];
        const bf16* Bs = lds[buf][1];
        bf16x8 bfr[2][4], af[2][4];
        #pragma unroll
        for (int kk = 0; kk < 2; kk++)
            #pragma unroll
            for (int n = 0; n < 4; n++) {
                int r = wn4 * 64 + n * 16 + l15;
                bfr[kk][n] = *(const bf16x8*)&Bs[r * 64 + ((kk * 32 + kbase) ^ rdxor)];
            }
        #pragma unroll
        for (int kk = 0; kk < 2; kk++)
            #pragma unroll
            for (int m = 0; m < 4; m++) {
                int r = wm2 * 128 + m * 16 + l15;
                af[kk][m] = *(const bf16x8*)&As[r * 64 + ((kk * 32 + kbase) ^ rdxor)];
            }
        __builtin_amdgcn_s_setprio(1);
        #pragma unroll
        for (int kk = 0; kk < 2; kk++)
            #pragma unroll
            for (int m = 0; m < 4; m++)
                #pragma unroll
                for (int n = 0; n < 4; n++)
                    acc[m][n] = __builtin_amdgcn_mfma_f32_16x16x32_bf16(af[kk][m], bfr[kk][n], acc[m][n], 0, 0, 0);
        __builtin_amdgcn_s_setprio(0);
        // second half of A rows
        #pragma unroll
        for (int kk = 0; kk < 2; kk++)
            #pragma unroll
            for (int m = 0; m < 4; m++) {
                int r = wm2 * 128 + 64 + m * 16 + l15;
                af[kk][m] = *(const bf16x8*)&As[r * 64 + ((kk * 32 + kbase) ^ rdxor)];
            }
        asm volatile("s_waitcnt lgkmcnt(0)" ::: "memory"); // all my buf reads done
        __builtin_amdgcn_sched_barrier(0);
        __builtin_amdgcn_s_barrier();             // ALL waves done reading buf
        if (t + 2 < NT) stage(t + 2);             // overwrite buf; flies across iters
        __builtin_amdgcn_s_setprio(1);
        #pragma unroll
        for (int kk = 0; kk < 2; kk++)
            #pragma unroll
            for (int m = 0; m < 4; m++)
                #pragma unroll
                for (int n = 0; n < 4; n++)
                    acc[4 + m][n] = __builtin_amdgcn_mfma_f32_16x16x32_bf16(af[kk][m], bfr[kk][n], acc[4 + m][n], 0, 0, 0);
        __builtin_amdgcn_s_setprio(0);
    }

    if constexpr (EPI == EPI_QKV) {
        // N=1536; 256-col panels are block-uniform: 0-1=Q, 2-3=K, 4-5=V.
        int region = (int)(colB0 >> 9);           // 0=Q, 1=K, 2=V
        if (region < 2) {
            bf16* dst = Cb + (long)region * (8192L * 512);
            int cb = ((int)colB0 & 511) + wn4 * 64;
            #pragma unroll
            for (int m = 0; m < 8; m++)
                #pragma unroll
                for (int n = 0; n < 4; n++)
                    #pragma unroll
                    for (int j = 0; j < 4; j++) {
                        long row = rowA0 + wm2 * 128 + m * 16 + (lane >> 4) * 4 + j;
                        int c = cb + n * 16 + l15;
                        dst[row * 512 + c] = (bf16)acc[m][n][j];
                    }
        } else {
            bf16* vtb = Cb + 2L * 8192 * 512;
            int cb = ((int)colB0 - 1024) + wn4 * 64;
            #pragma unroll
            for (int m = 0; m < 8; m++)
                #pragma unroll
                for (int n = 0; n < 4; n++) {
                    long k0 = rowA0 + wm2 * 128 + m * 16 + (lane >> 4) * 4;
                    long b = k0 >> 11, k = k0 & 2047;
                    int c = cb + n * 16 + l15;
                    bf16x4 pk = { (bf16)acc[m][n][0], (bf16)acc[m][n][1],
                                  (bf16)acc[m][n][2], (bf16)acc[m][n][3] };
                    *(bf16x4*)&vtb[(b * 512 + c) * 2048 + k] = pk;
                }
        }
    } else {
        #pragma unroll
        for (int m = 0; m < 8; m++) {
            #pragma unroll
            for (int n = 0; n < 4; n++) {
                #pragma unroll
                for (int j = 0; j < 4; j++) {
                    long row = rowA0 + wm2 * 128 + m * 16 + (lane >> 4) * 4 + j;
                    long col = colB0 + wn4 * 64 + n * 16 + l15;
                    float v = acc[m][n][j];
                    if (EPI == EPI_BIAS_F32) {
                        Cf[row * N + col] = v + bias[col];
                    } else if (EPI == EPI_BIAS_F32_NT) {
                        __builtin_nontemporal_store(v + bias[col], &Cf[row * N + col]);
                    } else if (EPI == EPI_BIAS_RELU_BF16) {
                        Cb[row * N + col] = (bf16)fmaxf(v + bias[col], 0.0f);
                    } else if (EPI == EPI_F32) {
                        Cf[row * N + col] = v;
                    }
                }
            }
        }
    }
}

// ---------------------------------------------------------------- vocab GEMM (R8 proven)
template<int BANDB>
__global__ __launch_bounds__(256)
void gemm128v(const bf16* __restrict__ A, const bf16* __restrict__ B,
              float* __restrict__ C, const float* __restrict__ bias,
              int N, int K) {
    const int NBR = 64;                            // 8192/128 row-tiles
    const int NT  = 8;                             // K=512 / 64
    int nwg = gridDim.x;                           // 16000 (%8==0)
    int lin = blockIdx.x;
    lin = (lin & 7) * (nwg >> 3) + (lin >> 3);     // XCD-contiguous chunks
    int per = BANDB * NBR;
    int band = lin / per, w2 = lin - band * per;
    int br = w2 / BANDB, bc = band * BANDB + (w2 - br * BANDB);

    __shared__ bf16 lds[2][2][128 * 64];           // 64 KiB -> 2 blocks/CU
    int tid = threadIdx.x;
    int lane = tid & 63, wid = tid >> 6;
    int wm = (wid >> 1) * 64, wn = (wid & 1) * 64;
    int rsub = lane >> 3;
    int csub = ((lane & 7) ^ rsub) * 8;            // pre-swizzled source col
    int rdsw = (lane & 7) * 8;                     // read-side XOR
    long rowA0 = (long)br * 128, colB0 = (long)bc * 128;
    const bf16* Abase = A + rowA0 * K;
    const bf16* Bbase = B + colB0 * K;
    f32x4 acc[4][4] = {};

    auto stage = [&](int t) {                      // 8 VMEM issues/thread
        int buf = t & 1;
        const bf16* Ag = Abase + t * 64;
        const bf16* Bg = Bbase + t * 64;
        #pragma unroll
        for (int i = 0; i < 4; i++) {
            int seg = wid * 4 + i;                 // 0..15
            long r = seg * 8 + rsub;
            gload_lds16(&Ag[r * K + csub], &lds[buf][0][seg * 512]);
        }
        #pragma unroll
        for (int i = 0; i < 4; i++) {
            int seg = wid * 4 + i;
            long r = seg * 8 + rsub;
            gload_lds16(&Bg[r * K + csub], &lds[buf][1][seg * 512]);
        }
    };

    stage(0);
    stage(1);

    for (int t = 0; t < NT; t++) {
        int buf = t & 1;
        if (t == NT - 1) asm volatile("s_waitcnt vmcnt(0)" ::: "memory");
        else             asm volatile("s_waitcnt vmcnt(8)" ::: "memory");
        __builtin_amdgcn_s_barrier();              // tile-t data visible
        const bf16* As = lds[buf][0];
        const bf16* Bs = lds[buf][1];
        __builtin_amdgcn_s_setprio(1);
        #pragma unroll
        for (int kk = 0; kk < 2; kk++) {
            bf16x8 af[4], bfr[4];
            int ko = (kk * 32 + (lane >> 4) * 8) ^ rdsw;
            #pragma unroll
            for (int m = 0; m < 4; m++) af[m]  = *(const bf16x8*)&As[(wm + m * 16 + (lane & 15)) * 64 + ko];
            #pragma unroll
            for (int n = 0; n < 4; n++) bfr[n] = *(const bf16x8*)&Bs[(wn + n * 16 + (lane & 15)) * 64 + ko];
            #pragma unroll
            for (int m = 0; m < 4; m++)
                #pragma unroll
                for (int n = 0; n < 4; n++)
                    acc[m][n] = __builtin_amdgcn_mfma_f32_16x16x32_bf16(af[m], bfr[n], acc[m][n], 0, 0, 0);
        }
        __builtin_amdgcn_s_setprio(0);
        asm volatile("s_waitcnt lgkmcnt(0)" ::: "memory"); // my buf reads done
        __builtin_amdgcn_sched_barrier(0);
        __builtin_amdgcn_s_barrier();              // ALL waves done reading buf
        if (t + 2 < NT) stage(t + 2);              // overwrite buf
    }

    #pragma unroll
    for (int m = 0; m < 4; m++) {
        #pragma unroll
        for (int n = 0; n < 4; n++) {
            int col = (int)colB0 + wn + n * 16 + (lane & 15);
            float bcol = bias[col];
            #pragma unroll
            for (int j = 0; j < 4; j++) {
                long row = rowA0 + wm + m * 16 + (lane >> 4) * 4 + j;
                __builtin_nontemporal_store(acc[m][n][j] + bcol, &C[row * N + col]);
            }
        }
    }
}

// ---------------------------------------------------------------- launch
extern "C" void kernel_launch(void* const* d_in, const int* in_sizes, int n_in,
                              void* d_out, int out_size, void* d_ws, size_t ws_size,
                              hipStream_t stream) {
    const int*   x       = (const int*)d_in[0];
    const float* word_emb = (const float*)d_in[1];
    const float* pos_emb  = (const float*)d_in[2];
    const float* Wq = (const float*)d_in[3];
    const float* Wk = (const float*)d_in[4];
    const float* Wv = (const float*)d_in[5];
    const float* g1 = (const float*)d_in[6];
    const float* b1 = (const float*)d_in[7];
    const float* w_ffn1 = (const float*)d_in[8];
    const float* b_ffn1 = (const float*)d_in[9];
    const float* w_ffn2 = (const float*)d_in[10];
    const float* b_ffn2 = (const float*)d_in[11];
    const float* g2 = (const float*)d_in[12];
    const float* b2 = (const float*)d_in[13];
    const float* w_vocab = (const float*)d_in[14];
    const float* b_vocab = (const float*)d_in[15];
    float* out = (float*)d_out;

    char* w = (char*)d_ws;
    auto alloc = [&](size_t bytes) { char* p = w; w += (bytes + 255) & ~255ULL; return p; };
    // NOTE: wqb/wkb/wvb must stay contiguous ([1536 x 512] fused weight);
    //       qb/kb/vt contiguous (EPI_QKV writes all three off qb);
    //       pvp = 4 contiguous bf16 [8192x512] buffers (ZB_PV chunk stride);
    //       ffn2p = 2 contiguous bf16 [8192x512] buffers (split-K sC).
    bf16* wqb   = (bf16*)alloc(512 * 512 * 2);
    bf16* wkb   = (bf16*)alloc(512 * 512 * 2);
    bf16* wvb   = (bf16*)alloc(512 * 512 * 2);
    bf16* w1b   = (bf16*)alloc(2048 * 512 * 2);
    bf16* w2b   = (bf16*)alloc(512 * 2048 * 2);
    bf16* wvocb = (bf16*)alloc((size_t)32000 * 512 * 2);
    bf16* embb  = (bf16*)alloc((size_t)8192 * 512 * 2);   // also final_b (aliased)
    bf16* qb    = (bf16*)alloc((size_t)8192 * 512 * 2);
    bf16* kb    = (bf16*)alloc((size_t)8192 * 512 * 2);   // also out1_b (aliased)
    bf16* vt    = (bf16*)alloc((size_t)8192 * 512 * 2);
    bf16* scoresb = (bf16*)alloc((size_t)4 * 2048 * 2048 * 2); // bf16 scores; also ffn1_b
    bf16* probs = (bf16*)alloc((size_t)4 * 2048 * 2048 * 2);
    bf16* pvp   = (bf16*)alloc((size_t)4 * 8192 * 512 * 2);   // PV partials x4 (bf16)
    bf16* ffn2p = (bf16*)alloc((size_t)2 * 8192 * 512 * 2);   // ffn2 partials x2 (bf16)
    bf16* ffn1b = scoresb;         // alias: scores dead after softmax
    bf16* out1b = kb;              // alias: kb dead after scores GEMM
    bf16* finalb = embb;           // alias: embb dead after ln1 (last reader)

    const float qscale = 0.044194173824159216f; // 1/sqrt(512)

    // merged: embedding (blocks 0..4095) + all six weight cvts (blocks 4096..5631)
    CvtArgs ca;
    ca.src[0] = Wq;      ca.dst[0] = wqb;   ca.n4[0] = 512 * 512 / 4;          ca.scale[0] = qscale;
    ca.src[1] = Wk;      ca.dst[1] = wkb;   ca.n4[1] = 512 * 512 / 4;          ca.scale[1] = 1.0f;
    ca.src[2] = Wv;      ca.dst[2] = wvb;   ca.n4[2] = 512 * 512 / 4;          ca.scale[2] = 1.0f;
    ca.src[3] = w_ffn1;  ca.dst[3] = w1b;   ca.n4[3] = 2048 * 512 / 4;         ca.scale[3] = 1.0f;
    ca.src[4] = w_ffn2;  ca.dst[4] = w2b;   ca.n4[4] = 512 * 2048 / 4;         ca.scale[4] = 1.0f;
    ca.src[5] = w_vocab; ca.dst[5] = wvocb; ca.n4[5] = (long)32000 * 512 / 4;  ca.scale[5] = 1.0f;
    embed_cvt<<<5632, 256, 0, stream>>>(ca, x, word_emb, pos_emb, embb);

    // fused Q|K|V projection: emb[8192x512] @ Wqkv^T[1536x512] -> qb,kb,vt
    gemm256<EPI_QKV, true, false, 0, 8><<<dim3(6, 32, 1), 512, 0, stream>>>(
        embb, wqb, nullptr, qb, nullptr, 1536, 512, 0, 0, 0);

    // scores = Q @ K^T: 128^2 tiles, causal skip, bf16 output.
    gemm_bt<EPI_BF16, true, false, false, ZB_BATCH><<<dim3(16, 16, 4), 256, 0, stream>>>(
        qb, kb, nullptr, scoresb, nullptr, 1.0f, 2048, 2048, 512, 512,
        (long)2048 * 512, (long)2048 * 512, (long)2048 * 2048);

    softmax_causal<<<8192, 256, 0, stream>>>(scoresb, probs);

    // context = P @ V, split-K x4 without atomics, bf16 partials pv0..pv3
    // (ctx values ~5e-3 scale: bf16 err ~2e-5, >100x below error floor).
    gemm_bt<EPI_BF16, false, false, false, ZB_PV><<<dim3(4, 16, 16), 256, 0, stream>>>(
        probs, vt, nullptr, pvp, nullptr, 1.0f, 2048, 512, 2048, 2048,
        (long)2048 * 2048, (long)512 * 2048, (long)2048 * 512);

    // ln1: residual = embb + pv0 (+ pv1/pv2/pv3 row-conditionally), all bf16 in
    ln_kernel<1, false><<<8192, 128, 0, stream>>>(
        embb, pvp, nullptr, g1, b1, out1b);

    // ffn1 = relu(out1 @ W1^T + b1)  -- 256^2 deep pipeline
    gemm256<EPI_BIAS_RELU_BF16, true, false, 0, 8><<<dim3(8, 32, 1), 512, 0, stream>>>(
        out1b, w1b, nullptr, ffn1b, b_ffn1, 2048, 512, 0, 0, 0);

    // ffn2 = ffn1 @ W2^T, split-K x2, bf16 partials; summed (+b_ffn2) in ln2.
    gemm_bt<EPI_BF16, false, false, false, ZB_BATCH><<<dim3(4, 64, 2), 256, 0, stream>>>(
        ffn1b, w2b, nullptr, ffn2p, nullptr, 1.0f, 8192, 512, 1024, 2048,
        1024, 1024, 8192L * 512);

    // ln2: residual = out1b + ffn2p[0] + ffn2p[1] + b_ffn2
    ln_kernel<2, true><<<8192, 128, 0, stream>>>(
        out1b, ffn2p, b_ffn2, g2, b2, finalb);

    // logits = final @ w_vocab^T + b_vocab  -- 128^2 double-buffered pipeline,
    // 2 blocks/CU, 25 bands of 10 bc-tiles, NT stores (R8 proven).
    gemm128v<10><<<16000, 256, 0, stream>>>(finalb, wvocb, out, b_vocab, 32000, 512);
}

// Round 14
// 497.897 us; speedup vs baseline: 1.1265x; 1.0125x over previous
//
#include <hip/hip_runtime.h>
#include <hip/hip_bf16.h>

typedef __bf16 bf16;
typedef __attribute__((ext_vector_type(4))) __bf16 bf16x4;
typedef __attribute__((ext_vector_type(8))) __bf16 bf16x8;
typedef __attribute__((ext_vector_type(4))) float f32x4;

__device__ inline void gload_lds16(const bf16* g, bf16* l) {
    __builtin_amdgcn_global_load_lds(
        (const __attribute__((address_space(1))) void*)g,
        (__attribute__((address_space(3))) void*)l, 16, 0, 0);
}

// ---------------------------------------------------------------- embed + weight cvt (merged)
struct CvtArgs {
    const float* src[6];
    bf16* dst[6];
    long n4[6];
    float scale[6];
};
// blocks 0..4095: embedding (2 rows each, bf16 only).
// blocks 4096..5631: weight cvts, blocks assigned PROPORTIONAL to tensor size
// (w_vocab carries 85% of cvt bytes; R13 gave it only 1/6 of blocks -> after
// other blocks drained, a ~256-block tail ran at ~1-2 TB/s).
__global__ void embed_cvt(CvtArgs a, const int* __restrict__ x,
                          const float* __restrict__ we, const float* __restrict__ pe,
                          bf16* __restrict__ emb_b) {
    int b = blockIdx.x;
    int tid = threadIdx.x;           // 256
    if (b < 4096) {
        int row = b * 2 + (tid >> 7);
        int c = tid & 127;
        int tok = x[row];
        int s = row & 2047;
        float4 w = ((const float4*)we)[(long)tok * 128 + c];
        float4 p = ((const float4*)pe)[(long)s * 128 + c];
        bf16x4 eb = { (bf16)(w.x + p.x), (bf16)(w.y + p.y),
                      (bf16)(w.z + p.z), (bf16)(w.w + p.w) };
        ((bf16x4*)emb_b)[(long)row * 128 + c] = eb;
    } else {
        int bb = b - 4096;           // 0..1535
        int j, b0, nb;
        if      (bb < 32)  { j = 0; b0 = 0;   nb = 32;   }
        else if (bb < 64)  { j = 1; b0 = 32;  nb = 32;   }
        else if (bb < 96)  { j = 2; b0 = 64;  nb = 32;   }
        else if (bb < 224) { j = 3; b0 = 96;  nb = 128;  }
        else if (bb < 352) { j = 4; b0 = 224; nb = 128;  }
        else               { j = 5; b0 = 352; nb = 1184; }
        int bx = bb - b0;
        const float* __restrict__ src = a.src[j];
        bf16* __restrict__ dst = a.dst[j];
        long n4 = a.n4[j];
        float sc = a.scale[j];
        long i = (long)bx * 256 + tid;
        long stride = (long)nb * 256;
        for (; i < n4; i += stride) {
            float4 v = ((const float4*)src)[i];
            bf16x4 o = { (bf16)(v.x * sc), (bf16)(v.y * sc), (bf16)(v.z * sc), (bf16)(v.w * sc) };
            ((bf16x4*)dst)[i] = o;
        }
    }
}

// ---------------------------------------------------------------- layernorm (bf16 trunk + partials)
// Residual = a + partials [+ rb(col bias)], all bf16 inputs, f32 math.
// C3: 1 = PV split-K x4: add c[k] (k=0..3, stride 8192*512 bf16) with k=0
//         always, k>=1 only for rows with (row&2047) >= k*512;
//     2 = ffn2 split-K x2: add c[0], c[1] always.
template<int C3, bool RBIAS>
__global__ void ln_kernel(const bf16* __restrict__ a, const bf16* __restrict__ c,
                          const float* __restrict__ rb,
                          const float* __restrict__ g, const float* __restrict__ bb,
                          bf16* __restrict__ ob) {
    int row = blockIdx.x;            // 8192
    int t   = threadIdx.x;           // 128
    bf16x4 av = ((const bf16x4*)a)[(long)row * 128 + t];
    float4 xv = { (float)av[0], (float)av[1], (float)av[2], (float)av[3] };
    if (C3 == 1) {
        int r = row & 2047;
        #pragma unroll
        for (int k = 0; k < 4; k++) {
            if (k == 0 || r >= k * 512) {
                bf16x4 cv = ((const bf16x4*)(c + (long)k * 8192 * 512))[(long)row * 128 + t];
                xv.x += (float)cv[0]; xv.y += (float)cv[1];
                xv.z += (float)cv[2]; xv.w += (float)cv[3];
            }
        }
    } else if (C3 == 2) {
        #pragma unroll
        for (int k = 0; k < 2; k++) {
            bf16x4 cv = ((const bf16x4*)(c + (long)k * 8192 * 512))[(long)row * 128 + t];
            xv.x += (float)cv[0]; xv.y += (float)cv[1];
            xv.z += (float)cv[2]; xv.w += (float)cv[3];
        }
    }
    if (RBIAS) {
        float4 rv = ((const float4*)rb)[t];
        xv.x += rv.x; xv.y += rv.y; xv.z += rv.z; xv.w += rv.w;
    }
    float s  = xv.x + xv.y + xv.z + xv.w;
    float sq = xv.x * xv.x + xv.y * xv.y + xv.z * xv.z + xv.w * xv.w;
    #pragma unroll
    for (int o = 32; o > 0; o >>= 1) {
        s  += __shfl_xor(s, o);
        sq += __shfl_xor(sq, o);
    }
    __shared__ float rs[2], rq[2];
    int wid = t >> 6;
    if ((t & 63) == 0) { rs[wid] = s; rq[wid] = sq; }
    __syncthreads();
    s = rs[0] + rs[1]; sq = rq[0] + rq[1];
    float mu   = s * (1.0f / 512.0f);
    float var  = sq * (1.0f / 512.0f) - mu * mu;
    float rstd = rsqrtf(var + 1e-5f);
    float4 gv = ((const float4*)g)[t];
    float4 bv = ((const float4*)bb)[t];
    bf16x4 yb = { (bf16)((xv.x - mu) * rstd * gv.x + bv.x),
                  (bf16)((xv.y - mu) * rstd * gv.y + bv.y),
                  (bf16)((xv.z - mu) * rstd * gv.z + bv.z),
                  (bf16)((xv.w - mu) * rstd * gv.w + bv.w) };
    ((bf16x4*)ob)[(long)row * 128 + t] = yb;
}

// ---------------------------------------------------------------- causal softmax (bf16 scores)
__global__ void softmax_causal(const bf16* __restrict__ sc, bf16* __restrict__ pr) {
    int row = blockIdx.x;            // 8192
    int z = row >> 11, q = row & 2047;
    const bf16* srow = sc + ((long)z * 2048 + q) * 2048;
    bf16*       prow = pr + ((long)z * 2048 + q) * 2048;
    int t = threadIdx.x;             // 256, each handles 8 cols
    float v[8];
    int c0 = t * 8;
    if (t <= (q >> 3)) {
        bf16x8 vb = *(const bf16x8*)&srow[c0];
        #pragma unroll
        for (int j = 0; j < 8; j++) v[j] = (float)vb[j];
    } else {
        #pragma unroll
        for (int j = 0; j < 8; j++) v[j] = -1e30f;
    }
    float mx = -1e30f;
    #pragma unroll
    for (int j = 0; j < 8; j++) {
        if (c0 + j > q) v[j] = -1e30f;
        mx = fmaxf(mx, v[j]);
    }
    int lane = t & 63, wid = t >> 6;
    #pragma unroll
    for (int o = 32; o > 0; o >>= 1) mx = fmaxf(mx, __shfl_xor(mx, o));
    __shared__ float redm[4], reds[4];
    if (lane == 0) redm[wid] = mx;
    __syncthreads();
    mx = fmaxf(fmaxf(redm[0], redm[1]), fmaxf(redm[2], redm[3]));
    float p[8]; float sum = 0.f;
    #pragma unroll
    for (int j = 0; j < 8; j++) {
        p[j] = (c0 + j <= q) ? __expf(v[j] - mx) : 0.f;
        sum += p[j];
    }
    #pragma unroll
    for (int o = 32; o > 0; o >>= 1) sum += __shfl_xor(sum, o);
    if (lane == 0) reds[wid] = sum;
    __syncthreads();
    sum = reds[0] + reds[1] + reds[2] + reds[3];
    float inv = 1.0f / sum;
    int wlim = ((q >> 7) + 1) * 128;             // causal 128-block boundary
    if (c0 < wlim) {
        bf16x8 o;
        #pragma unroll
        for (int j = 0; j < 8; j++) o[j] = (bf16)(p[j] * inv);
        *(bf16x8*)&prow[c0] = o;
    }
}

// ---------------------------------------------------------------- epilogue tags
enum { EPI_F32 = 0, EPI_BF16 = 1, EPI_VT = 2, EPI_BIAS_RELU_BF16 = 3, EPI_BIAS_F32 = 4,
       EPI_QKV = 5, EPI_BIAS_F32_NT = 6 };
enum { ZB_BATCH = 0, ZB_PV = 1 };

// ---------------------------------------------------------------- 128^2 GEMM (proven)
// ZB_BATCH: z = batch (or K-chunk); A/B/Cf/Cb shifted by z*sA/sB/sC elements.
// ZB_PV   : z = batch*4 + chunk. Causal P@V with split-K chunks of 512:
//           chunk c covers k in [c*512, min(keff, c*512+512)).
//           C base for chunk c is +c*8192*512 (pv0..pv3 contiguous);
//           blocks whose causal keff <= lo exit early (block-uniform).
template<int EPI, bool CAUSAL_SKIP, bool CAUSAL_K, bool XCD, int ZMODE>
__global__ __launch_bounds__(256)
void gemm_bt(const bf16* __restrict__ A, const bf16* __restrict__ B,
             float* __restrict__ Cf, bf16* __restrict__ Cb,
             const float* __restrict__ bias, float scale,
             int M, int N, int K, int Krow, long sA, long sB, long sC) {
    int br, bc;
    if (XCD) {
        int nwg = gridDim.x * gridDim.y;         // caller ensures %8==0
        int lin = blockIdx.y * gridDim.x + blockIdx.x;
        lin = (lin & 7) * (nwg >> 3) + (lin >> 3);
        br = lin / gridDim.x; bc = lin - br * gridDim.x;
    } else { br = blockIdx.y; bc = blockIdx.x; }
    int z = blockIdx.z;
    int Kext = K;
    if (ZMODE == ZB_BATCH) {
        A += (long)z * sA; B += (long)z * sB; Cf += (long)z * sC; Cb += (long)z * sC;
    } else if (ZMODE == ZB_PV) {
        int batch = z >> 2, chunk = z & 3;
        A += (long)batch * sA; B += (long)batch * sB;
        Cf += (long)chunk * (8192L * 512) + (long)batch * sC;
        Cb += (long)chunk * (8192L * 512) + (long)batch * sC;
        int keff = min(K, (br + 1) * 128);
        int lo = chunk * 512;
        if (keff <= lo) return;                  // block-uniform early exit
        A += lo; B += lo;
        Kext = min(keff, lo + 512) - lo;
    }
    if (CAUSAL_SKIP && bc > br) return;
    if (CAUSAL_K) Kext = min(Kext, (br + 1) * 128);
    __shared__ bf16 As[128 * 64];
    __shared__ bf16 Bs[128 * 64];
    int tid = threadIdx.x;
    int lane = tid & 63, wid = tid >> 6;
    int wm = (wid >> 1) * 64, wn = (wid & 1) * 64;
    f32x4 acc[4][4] = {};
    int rowA0 = br * 128, colB0 = bc * 128;
    int rsub = lane >> 3;
    int csub = ((lane & 7) ^ rsub) * 8;            // pre-swizzled source col
    int rdsw = (lane & 7) * 8;                     // read-side XOR
    for (int kt = 0; kt < Kext; kt += 64) {
        const bf16* Ag = A + (long)rowA0 * Krow + kt;
        const bf16* Bg = B + (long)colB0 * Krow + kt;
        #pragma unroll
        for (int i = 0; i < 4; i++) {
            int seg = wid * 4 + i;
            int r = seg * 8 + rsub;
            gload_lds16(&Ag[(long)r * Krow + csub], &As[seg * 512]);
            gload_lds16(&Bg[(long)r * Krow + csub], &Bs[seg * 512]);
        }
        __syncthreads();
        #pragma unroll
        for (int kk = 0; kk < 2; kk++) {
            bf16x8 af[4], bfr[4];
            int ko = (kk * 32 + (lane >> 4) * 8) ^ rdsw;
            #pragma unroll
            for (int m = 0; m < 4; m++) af[m]  = *(const bf16x8*)&As[(wm + m * 16 + (lane & 15)) * 64 + ko];
            #pragma unroll
            for (int n = 0; n < 4; n++) bfr[n] = *(const bf16x8*)&Bs[(wn + n * 16 + (lane & 15)) * 64 + ko];
            #pragma unroll
            for (int m = 0; m < 4; m++)
                #pragma unroll
                for (int n = 0; n < 4; n++)
                    acc[m][n] = __builtin_amdgcn_mfma_f32_16x16x32_bf16(af[m], bfr[n], acc[m][n], 0, 0, 0);
        }
        __syncthreads();
    }
    #pragma unroll
    for (int m = 0; m < 4; m++) {
        #pragma unroll
        for (int n = 0; n < 4; n++) {
            #pragma unroll
            for (int j = 0; j < 4; j++) {
                int row = rowA0 + wm + m * 16 + (lane >> 4) * 4 + j;
                int col = colB0 + wn + n * 16 + (lane & 15);
                float v = acc[m][n][j];
                if (EPI == EPI_F32) {
                    Cf[(long)row * N + col] = v;        // z-offsets already applied
                } else if (EPI == EPI_BF16) {
                    Cb[(long)row * N + col] = (bf16)(v * scale);
                } else if (EPI == EPI_VT) {
                    int b = row >> 11, k = row & 2047;
                    Cb[((long)b * 512 + col) * 2048 + k] = (bf16)v;
                } else if (EPI == EPI_BIAS_RELU_BF16) {
                    float y = fmaxf(v + bias[col], 0.0f);
                    Cb[(long)row * N + col] = (bf16)y;
                } else if (EPI == EPI_BIAS_F32) {
                    Cf[(long)row * N + col] = v + bias[col];
                }
            }
        }
    }
}

// ---------------------------------------------------------------- 256^2 deep-pipeline GEMM (BK=64)
template<int EPI, bool XCD, bool CSKIP, int BANDW, int NT>
__global__ __launch_bounds__(512)
void gemm256(const bf16* __restrict__ A, const bf16* __restrict__ B,
             float* __restrict__ Cf, bf16* __restrict__ Cb,
             const float* __restrict__ bias, int N, int K,
             long sA, long sB, long sC) {
    int br, bc;
    if (XCD) {
        int nwg = gridDim.x * gridDim.y;          // caller ensures %8==0
        int lin = blockIdx.y * gridDim.x + blockIdx.x;
        lin = (lin & 7) * (nwg >> 3) + (lin >> 3);
        if (BANDW > 0) {
            int per = BANDW * gridDim.y;          // blocks per band
            int band = lin / per, w2 = lin - band * per;
            br = w2 / BANDW; bc = band * BANDW + (w2 - br * BANDW);
        } else {
            br = lin / gridDim.x; bc = lin - br * gridDim.x;
        }
    } else { br = blockIdx.y; bc = blockIdx.x; }
    if (CSKIP && bc > br) return;                 // causal skip at 256-tile granularity
    int z = blockIdx.z;
    A  += (long)z * sA;
    B  += (long)z * sB;
    Cf += (long)z * sC;
    __shared__ bf16 lds[2][2][256 * 64];          // [buf][A/B] = 128 KiB
    int tid = threadIdx.x;
    int lane = tid & 63, wid = tid >> 6;
    int wm2 = wid >> 2, wn4 = wid & 3;
    long rowA0 = (long)br * 256, colB0 = (long)bc * 256;
    int rsub = lane >> 3;
    int csw  = ((lane & 7) ^ rsub) * 8;           // pre-swizzled source col
    int l15 = lane & 15;
    int rdxor = (lane & 7) << 3;
    int kbase = (lane >> 4) * 8;
    const bf16* Abase = A + rowA0 * K;
    const bf16* Bbase = B + colB0 * K;
    f32x4 acc[8][4] = {};

    auto stage = [&](int t) {
        int buf = t & 1;
        const bf16* Ag = Abase + t * 64;
        const bf16* Bg = Bbase + t * 64;
        #pragma unroll
        for (int i = 0; i < 4; i++) {
            int seg = wid * 4 + i;                // 0..31
            long r = seg * 8 + rsub;
            gload_lds16(&Ag[r * K + csw], &lds[buf][0][seg * 512]);
        }
        #pragma unroll
        for (int i = 0; i < 4; i++) {
            int seg = wid * 4 + i;
            long r = seg * 8 + rsub;
            gload_lds16(&Bg[r * K + csw], &lds[buf][1][seg * 512]);
        }
    };

    stage(0);
    stage(1);

    for (int t = 0; t < NT; t++) {
        int buf = t & 1;
        if (t == NT - 1) asm volatile("s_waitcnt vmcnt(0)" ::: "memory");
        else             asm volatile("s_waitcnt vmcnt(8)" ::: "memory");
        __builtin_amdgcn_s_barrier();             // everyone's tile-t data visible
        const bf16* As = lds[buf][0];
        const bf16* Bs = lds[buf][1];
        bf16x8 bfr[2][4], af[2][4];
        #pragma unroll
        for (int kk = 0; kk < 2; kk++)
            #pragma unroll
            for (int n = 0; n < 4; n++) {
                int r = wn4 * 64 + n * 16 + l15;
                bfr[kk][n] = *(const bf16x8*)&Bs[r * 64 + ((kk * 32 + kbase) ^ rdxor)];
            }
        #pragma unroll
        for (int kk = 0; kk < 2; kk++)
            #pragma unroll
            for (int m = 0; m < 4; m++) {
                int r = wm2 * 128 + m * 16 + l15;
                af[kk][m] = *(const bf16x8*)&As[r * 64 + ((kk * 32 + kbase) ^ rdxor)];
            }
        __builtin_amdgcn_s_setprio(1);
        #pragma unroll
        for (int kk = 0; kk < 2; kk++)
            #pragma unroll
            for (int m = 0; m < 4; m++)
                #pragma unroll
                for (int n = 0; n < 4; n++)
                    acc[m][n] = __builtin_amdgcn_mfma_f32_16x16x32_bf16(af[kk][m], bfr[kk][n], acc[m][n], 0, 0, 0);
        __builtin_amdgcn_s_setprio(0);
        // second half of A rows
        #pragma unroll
        for (int kk = 0; kk < 2; kk++)
            #pragma unroll
            for (int m = 0; m < 4; m++) {
                int r = wm2 * 128 + 64 + m * 16 + l15;
                af[kk][m] = *(const bf16x8*)&As[r * 64 + ((kk * 32 + kbase) ^ rdxor)];
            }
        asm volatile("s_waitcnt lgkmcnt(0)" ::: "memory"); // all my buf reads done
        __builtin_amdgcn_sched_barrier(0);
        __builtin_amdgcn_s_barrier();             // ALL waves done reading buf
        if (t + 2 < NT) stage(t + 2);             // overwrite buf; flies across iters
        __builtin_amdgcn_s_setprio(1);
        #pragma unroll
        for (int kk = 0; kk < 2; kk++)
            #pragma unroll
            for (int m = 0; m < 4; m++)
                #pragma unroll
                for (int n = 0; n < 4; n++)
                    acc[4 + m][n] = __builtin_amdgcn_mfma_f32_16x16x32_bf16(af[kk][m], bfr[kk][n], acc[4 + m][n], 0, 0, 0);
        __builtin_amdgcn_s_setprio(0);
    }

    if constexpr (EPI == EPI_QKV) {
        // N=1536; 256-col panels are block-uniform: 0-1=Q, 2-3=K, 4-5=V.
        int region = (int)(colB0 >> 9);           // 0=Q, 1=K, 2=V
        if (region < 2) {
            bf16* dst = Cb + (long)region * (8192L * 512);
            int cb = ((int)colB0 & 511) + wn4 * 64;
            #pragma unroll
            for (int m = 0; m < 8; m++)
                #pragma unroll
                for (int n = 0; n < 4; n++)
                    #pragma unroll
                    for (int j = 0; j < 4; j++) {
                        long row = rowA0 + wm2 * 128 + m * 16 + (lane >> 4) * 4 + j;
                        int c = cb + n * 16 + l15;
                        dst[row * 512 + c] = (bf16)acc[m][n][j];
                    }
        } else {
            bf16* vtb = Cb + 2L * 8192 * 512;
            int cb = ((int)colB0 - 1024) + wn4 * 64;
            #pragma unroll
            for (int m = 0; m < 8; m++)
                #pragma unroll
                for (int n = 0; n < 4; n++) {
                    long k0 = rowA0 + wm2 * 128 + m * 16 + (lane >> 4) * 4;
                    long b = k0 >> 11, k = k0 & 2047;
                    int c = cb + n * 16 + l15;
                    bf16x4 pk = { (bf16)acc[m][n][0], (bf16)acc[m][n][1],
                                  (bf16)acc[m][n][2], (bf16)acc[m][n][3] };
                    *(bf16x4*)&vtb[(b * 512 + c) * 2048 + k] = pk;
                }
        }
    } else {
        #pragma unroll
        for (int m = 0; m < 8; m++) {
            #pragma unroll
            for (int n = 0; n < 4; n++) {
                #pragma unroll
                for (int j = 0; j < 4; j++) {
                    long row = rowA0 + wm2 * 128 + m * 16 + (lane >> 4) * 4 + j;
                    long col = colB0 + wn4 * 64 + n * 16 + l15;
                    float v = acc[m][n][j];
                    if (EPI == EPI_BIAS_F32) {
                        Cf[row * N + col] = v + bias[col];
                    } else if (EPI == EPI_BIAS_F32_NT) {
                        __builtin_nontemporal_store(v + bias[col], &Cf[row * N + col]);
                    } else if (EPI == EPI_BIAS_RELU_BF16) {
                        Cb[row * N + col] = (bf16)fmaxf(v + bias[col], 0.0f);
                    } else if (EPI == EPI_F32) {
                        Cf[row * N + col] = v;
                    }
                }
            }
        }
    }
}

// ---------------------------------------------------------------- vocab GEMM (R8 proven)
template<int BANDB>
__global__ __launch_bounds__(256)
void gemm128v(const bf16* __restrict__ A, const bf16* __restrict__ B,
              float* __restrict__ C, const float* __restrict__ bias,
              int N, int K) {
    const int NBR = 64;                            // 8192/128 row-tiles
    const int NT  = 8;                             // K=512 / 64
    int nwg = gridDim.x;                           // 16000 (%8==0)
    int lin = blockIdx.x;
    lin = (lin & 7) * (nwg >> 3) + (lin >> 3);     // XCD-contiguous chunks
    int per = BANDB * NBR;
    int band = lin / per, w2 = lin - band * per;
    int br = w2 / BANDB, bc = band * BANDB + (w2 - br * BANDB);

    __shared__ bf16 lds[2][2][128 * 64];           // 64 KiB -> 2 blocks/CU
    int tid = threadIdx.x;
    int lane = tid & 63, wid = tid >> 6;
    int wm = (wid >> 1) * 64, wn = (wid & 1) * 64;
    int rsub = lane >> 3;
    int csub = ((lane & 7) ^ rsub) * 8;            // pre-swizzled source col
    int rdsw = (lane & 7) * 8;                     // read-side XOR
    long rowA0 = (long)br * 128, colB0 = (long)bc * 128;
    const bf16* Abase = A + rowA0 * K;
    const bf16* Bbase = B + colB0 * K;
    f32x4 acc[4][4] = {};

    auto stage = [&](int t) {                      // 8 VMEM issues/thread
        int buf = t & 1;
        const bf16* Ag = Abase + t * 64;
        const bf16* Bg = Bbase + t * 64;
        #pragma unroll
        for (int i = 0; i < 4; i++) {
            int seg = wid * 4 + i;                 // 0..15
            long r = seg * 8 + rsub;
            gload_lds16(&Ag[r * K + csub], &lds[buf][0][seg * 512]);
        }
        #pragma unroll
        for (int i = 0; i < 4; i++) {
            int seg = wid * 4 + i;
            long r = seg * 8 + rsub;
            gload_lds16(&Bg[r * K + csub], &lds[buf][1][seg * 512]);
        }
    };

    stage(0);
    stage(1);

    for (int t = 0; t < NT; t++) {
        int buf = t & 1;
        if (t == NT - 1) asm volatile("s_waitcnt vmcnt(0)" ::: "memory");
        else             asm volatile("s_waitcnt vmcnt(8)" ::: "memory");
        __builtin_amdgcn_s_barrier();              // tile-t data visible
        const bf16* As = lds[buf][0];
        const bf16* Bs = lds[buf][1];
        __builtin_amdgcn_s_setprio(1);
        #pragma unroll
        for (int kk = 0; kk < 2; kk++) {
            bf16x8 af[4], bfr[4];
            int ko = (kk * 32 + (lane >> 4) * 8) ^ rdsw;
            #pragma unroll
            for (int m = 0; m < 4; m++) af[m]  = *(const bf16x8*)&As[(wm + m * 16 + (lane & 15)) * 64 + ko];
            #pragma unroll
            for (int n = 0; n < 4; n++) bfr[n] = *(const bf16x8*)&Bs[(wn + n * 16 + (lane & 15)) * 64 + ko];
            #pragma unroll
            for (int m = 0; m < 4; m++)
                #pragma unroll
                for (int n = 0; n < 4; n++)
                    acc[m][n] = __builtin_amdgcn_mfma_f32_16x16x32_bf16(af[m], bfr[n], acc[m][n], 0, 0, 0);
        }
        __builtin_amdgcn_s_setprio(0);
        asm volatile("s_waitcnt lgkmcnt(0)" ::: "memory"); // my buf reads done
        __builtin_amdgcn_sched_barrier(0);
        __builtin_amdgcn_s_barrier();              // ALL waves done reading buf
        if (t + 2 < NT) stage(t + 2);              // overwrite buf
    }

    #pragma unroll
    for (int m = 0; m < 4; m++) {
        #pragma unroll
        for (int n = 0; n < 4; n++) {
            int col = (int)colB0 + wn + n * 16 + (lane & 15);
            float bcol = bias[col];
            #pragma unroll
            for (int j = 0; j < 4; j++) {
                long row = rowA0 + wm + m * 16 + (lane >> 4) * 4 + j;
                __builtin_nontemporal_store(acc[m][n][j] + bcol, &C[row * N + col]);
            }
        }
    }
}

// ---------------------------------------------------------------- launch
extern "C" void kernel_launch(void* const* d_in, const int* in_sizes, int n_in,
                              void* d_out, int out_size, void* d_ws, size_t ws_size,
                              hipStream_t stream) {
    const int*   x       = (const int*)d_in[0];
    const float* word_emb = (const float*)d_in[1];
    const float* pos_emb  = (const float*)d_in[2];
    const float* Wq = (const float*)d_in[3];
    const float* Wk = (const float*)d_in[4];
    const float* Wv = (const float*)d_in[5];
    const float* g1 = (const float*)d_in[6];
    const float* b1 = (const float*)d_in[7];
    const float* w_ffn1 = (const float*)d_in[8];
    const float* b_ffn1 = (const float*)d_in[9];
    const float* w_ffn2 = (const float*)d_in[10];
    const float* b_ffn2 = (const float*)d_in[11];
    const float* g2 = (const float*)d_in[12];
    const float* b2 = (const float*)d_in[13];
    const float* w_vocab = (const float*)d_in[14];
    const float* b_vocab = (const float*)d_in[15];
    float* out = (float*)d_out;

    char* w = (char*)d_ws;
    auto alloc = [&](size_t bytes) { char* p = w; w += (bytes + 255) & ~255ULL; return p; };
    // NOTE: wqb/wkb/wvb must stay contiguous ([1536 x 512] fused weight);
    //       qb/kb/vt contiguous (EPI_QKV writes all three off qb);
    //       pvp = 4 contiguous bf16 [8192x512] buffers (ZB_PV chunk stride);
    //       ffn2p = 2 contiguous bf16 [8192x512] buffers (split-K sC).
    bf16* wqb   = (bf16*)alloc(512 * 512 * 2);
    bf16* wkb   = (bf16*)alloc(512 * 512 * 2);
    bf16* wvb   = (bf16*)alloc(512 * 512 * 2);
    bf16* w1b   = (bf16*)alloc(2048 * 512 * 2);
    bf16* w2b   = (bf16*)alloc(512 * 2048 * 2);
    bf16* wvocb = (bf16*)alloc((size_t)32000 * 512 * 2);
    bf16* embb  = (bf16*)alloc((size_t)8192 * 512 * 2);   // also final_b (aliased)
    bf16* qb    = (bf16*)alloc((size_t)8192 * 512 * 2);
    bf16* kb    = (bf16*)alloc((size_t)8192 * 512 * 2);   // also out1_b (aliased)
    bf16* vt    = (bf16*)alloc((size_t)8192 * 512 * 2);
    bf16* scoresb = (bf16*)alloc((size_t)4 * 2048 * 2048 * 2); // bf16 scores; also ffn1_b
    bf16* probs = (bf16*)alloc((size_t)4 * 2048 * 2048 * 2);
    bf16* pvp   = (bf16*)alloc((size_t)4 * 8192 * 512 * 2);   // PV partials x4 (bf16)
    bf16* ffn2p = (bf16*)alloc((size_t)2 * 8192 * 512 * 2);   // ffn2 partials x2 (bf16)
    bf16* ffn1b = scoresb;         // alias: scores dead after softmax
    bf16* out1b = kb;              // alias: kb dead after scores GEMM
    bf16* finalb = embb;           // alias: embb dead after ln1 (last reader)

    const float qscale = 0.044194173824159216f; // 1/sqrt(512)

    // merged: embedding (blocks 0..4095) + size-balanced weight cvts (4096..5631)
    CvtArgs ca;
    ca.src[0] = Wq;      ca.dst[0] = wqb;   ca.n4[0] = 512 * 512 / 4;          ca.scale[0] = qscale;
    ca.src[1] = Wk;      ca.dst[1] = wkb;   ca.n4[1] = 512 * 512 / 4;          ca.scale[1] = 1.0f;
    ca.src[2] = Wv;      ca.dst[2] = wvb;   ca.n4[2] = 512 * 512 / 4;          ca.scale[2] = 1.0f;
    ca.src[3] = w_ffn1;  ca.dst[3] = w1b;   ca.n4[3] = 2048 * 512 / 4;         ca.scale[3] = 1.0f;
    ca.src[4] = w_ffn2;  ca.dst[4] = w2b;   ca.n4[4] = 512 * 2048 / 4;         ca.scale[4] = 1.0f;
    ca.src[5] = w_vocab; ca.dst[5] = wvocb; ca.n4[5] = (long)32000 * 512 / 4;  ca.scale[5] = 1.0f;
    embed_cvt<<<5632, 256, 0, stream>>>(ca, x, word_emb, pos_emb, embb);

    // fused Q|K|V projection: emb[8192x512] @ Wqkv^T[1536x512] -> qb,kb,vt
    gemm256<EPI_QKV, true, false, 0, 8><<<dim3(6, 32, 1), 512, 0, stream>>>(
        embb, wqb, nullptr, qb, nullptr, 1536, 512, 0, 0, 0);

    // scores = Q @ K^T: 128^2 tiles, causal skip, bf16 output.
    gemm_bt<EPI_BF16, true, false, false, ZB_BATCH><<<dim3(16, 16, 4), 256, 0, stream>>>(
        qb, kb, nullptr, scoresb, nullptr, 1.0f, 2048, 2048, 512, 512,
        (long)2048 * 512, (long)2048 * 512, (long)2048 * 2048);

    softmax_causal<<<8192, 256, 0, stream>>>(scoresb, probs);

    // context = P @ V, split-K x4 without atomics, bf16 partials pv0..pv3.
    gemm_bt<EPI_BF16, false, false, false, ZB_PV><<<dim3(4, 16, 16), 256, 0, stream>>>(
        probs, vt, nullptr, pvp, nullptr, 1.0f, 2048, 512, 2048, 2048,
        (long)2048 * 2048, (long)512 * 2048, (long)2048 * 512);

    // ln1: residual = embb + pv0 (+ pv1/pv2/pv3 row-conditionally), all bf16 in
    ln_kernel<1, false><<<8192, 128, 0, stream>>>(
        embb, pvp, nullptr, g1, b1, out1b);

    // ffn1 = relu(out1 @ W1^T + b1)  -- 256^2 deep pipeline
    gemm256<EPI_BIAS_RELU_BF16, true, false, 0, 8><<<dim3(8, 32, 1), 512, 0, stream>>>(
        out1b, w1b, nullptr, ffn1b, b_ffn1, 2048, 512, 0, 0, 0);

    // ffn2 = ffn1 @ W2^T, split-K x2, bf16 partials; summed (+b_ffn2) in ln2.
    gemm_bt<EPI_BF16, false, false, false, ZB_BATCH><<<dim3(4, 64, 2), 256, 0, stream>>>(
        ffn1b, w2b, nullptr, ffn2p, nullptr, 1.0f, 8192, 512, 1024, 2048,
        1024, 1024, 8192L * 512);

    // ln2: residual = out1b + ffn2p[0] + ffn2p[1] + b_ffn2
    ln_kernel<2, true><<<8192, 128, 0, stream>>>(
        out1b, ffn2p, b_ffn2, g2, b2, finalb);

    // logits = final @ w_vocab^T + b_vocab  -- 128^2 double-buffered pipeline,
    // 2 blocks/CU, 25 bands of 10 bc-tiles, NT stores (R8 proven).
    gemm128v<10><<<16000, 256, 0, stream>>>(finalb, wvocb, out, b_vocab, 32000, 512);
}